// Round 3
// baseline (2026.244 us; speedup 1.0000x reference)
//
#include <hip/hip_runtime.h>
#include <math.h>

typedef __attribute__((ext_vector_type(8))) short short8;
typedef __attribute__((ext_vector_type(4))) float f32x4;

#define NB 64
#define NS 128
#define NE 512
#define NH 512
#define NPOI_ 8192
#define NCAT_ 400
#define NF_ 128
#define H3 1536
#define NEGV -1000000000.0
#define NWG_SCAN 128

__device__ inline float sigmf(float x){ return 1.0f/(1.0f + expf(-x)); }
__device__ inline unsigned short f2bf(float f){
    unsigned u = __float_as_uint(f);
    unsigned r = (u + 0x7fffu + ((u>>16)&1u)) >> 16;
    return (unsigned short)r;
}

// ---------- f32 -> bf16 conversion (n multiple of 4) ----------
__global__ void k_cvt(const float* __restrict__ in, unsigned short* __restrict__ out, int n){
    int t = blockIdx.x*blockDim.x + threadIdx.x;
    int i = t*4;
    if (i < n){
        float4 v = *(const float4*)(in + i);
        ushort4 o;
        o.x = f2bf(v.x); o.y = f2bf(v.y); o.z = f2bf(v.z); o.w = f2bf(v.w);
        *(ushort4*)(out + i) = o;
    }
}

__global__ void k_zero(int* p){ if (threadIdx.x == 0 && blockIdx.x == 0) *p = 0; }

// ---------- phase 1: attention precompute (f64 for argmax stability) ----------
__global__ void k_prep_c(const float* __restrict__ W_attn, const float* __restrict__ a_attn,
                         double* __restrict__ c1d, double* __restrict__ c2d){
    int f = blockIdx.x*blockDim.x + threadIdx.x;
    if (f < NF_){
        double s1=0.0, s2=0.0;
        for (int k=0;k<NF_;k++){
            double w = (double)W_attn[f*NF_+k];
            s1 += w*(double)a_attn[k];
            s2 += w*(double)a_attn[NF_+k];
        }
        c1d[f]=s1; c2d[f]=s2;
    }
}

__global__ void k_wh(const float* __restrict__ X, const double* __restrict__ c1d,
                     const double* __restrict__ c2d, double* __restrict__ wh1, double* __restrict__ wh2){
    int p = blockIdx.x*blockDim.x + threadIdx.x;
    if (p < NPOI_){
        const float* x = X + (size_t)p*NF_;
        double s1=0.0,s2=0.0;
        for (int k=0;k<NF_;k++){ double xv=(double)x[k]; s1+=xv*c1d[k]; s2+=xv*c2d[k]; }
        wh1[p]=s1; wh2[p]=s2;
    }
}

__global__ void k_gh0(const float* __restrict__ h0, const float* __restrict__ W_hh,
                      const float* __restrict__ b_hh, float* __restrict__ gh0){
    int c = blockIdx.x*blockDim.x + threadIdx.x;
    if (c < H3){
        const float* w = W_hh + (size_t)c*NH;
        float s=0.f;
        for (int k=0;k<NH;k++) s += h0[k]*w[k];
        gh0[c] = s + b_hh[c];
    }
}

__device__ inline double shfl_down_d(double x, int off){
    long long v = __double_as_longlong(x);
    int lo = (int)(v & 0xffffffffLL), hi = (int)(((unsigned long long)v)>>32);
    lo = __shfl_down(lo, off); hi = __shfl_down(hi, off);
    return __longlong_as_double(((long long)hi<<32) | (unsigned long long)(unsigned int)lo);
}

__global__ void k_attn(const int* __restrict__ seq, const int* __restrict__ lens,
                       const float* __restrict__ A, const double* __restrict__ wh1,
                       const double* __restrict__ wh2, float* __restrict__ alpha,
                       int* __restrict__ idxout){
    int gw = (int)((blockIdx.x*(size_t)blockDim.x + threadIdx.x) >> 6);
    int lane = threadIdx.x & 63;
    if (gw >= NB*NS) return;
    int b = gw >> 7, j = gw & 127;
    int len = lens[b];
    int q = seq[b*NS + j];
    double wq = wh2[q];
    bool jvalid = (j < len);
    double mval = -1.0e300; int mk = 0;
    for (int k0=0;k0<NS;k0+=64){
        int k = k0 + lane;
        double val = NEGV;
        if (k < j && jvalid){
            int p = seq[b*NS + k];
            double e = wh1[p] + wq;
            e = (e > 0.0) ? e : 0.2*e;
            val = e * ((double)A[(size_t)p*NPOI_ + q] + 1.0);
        }
        if (val > mval){ mval = val; mk = k; }
    }
    for (int off=32; off; off>>=1){
        double ov = shfl_down_d(mval, off);
        int ok = __shfl_down(mk, off);
        if (ov > mval || (ov == mval && ok < mk)){ mval = ov; mk = ok; }
    }
    if (lane == 0){
        double v0 = mval;
        double v1;
        if (j == 0) v1 = 0.0;
        else if (!jvalid) v1 = NEGV;
        else {
            int p = seq[b*NS + j - 1];
            double e = wh1[p] + wq;
            e = (e > 0.0) ? e : 0.2*e;
            v1 = e * ((double)A[(size_t)p*NPOI_ + q] + 1.0);
        }
        double m = fmax(v0, v1);
        double e0 = exp(v0 - m), e1 = exp(v1 - m);
        double den = e0 + e1;
        alpha[(size_t)(b*NS+j)*2 + 0] = (float)(e0/den);
        alpha[(size_t)(b*NS+j)*2 + 1] = (float)(e1/den);
        idxout[b*NS + j] = mk;
    }
}

// ---------- bf16 MFMA NT GEMM: C[r,c] = sum_k A[r,k]*B[c,k] + bias[c] ----------
#define LDT 88
__global__ __launch_bounds__(256) void k_gemm_bf16(const unsigned short* __restrict__ A,
        const unsigned short* __restrict__ B, const float* __restrict__ bias,
        float* __restrict__ C, int M, int N, int K, int ldc){
    __shared__ unsigned short As[128][LDT];
    __shared__ unsigned short Bs[128][LDT];
    int row0 = blockIdx.y*128, col0 = blockIdx.x*128;
    int tid = threadIdx.x;
    int lane = tid & 63, w = tid >> 6;
    int wr = w >> 1, wc = w & 1;
    int lr = lane & 15, lk = lane >> 4;
    f32x4 acc[4][4] = {};
    for (int k0 = 0; k0 < K; k0 += 64){
        #pragma unroll
        for (int q = 0; q < 4; q++){
            int c = tid + 256*q;
            int r = c >> 3, ko = (c & 7)*8;
            *(short8*)&As[r][ko] = *(const short8*)(A + (size_t)(row0+r)*K + k0 + ko);
            int gc = col0 + r;
            short8 bv = {};
            if (gc < N) bv = *(const short8*)(B + (size_t)gc*K + k0 + ko);
            *(short8*)&Bs[r][ko] = bv;
        }
        __syncthreads();
        #pragma unroll
        for (int ks = 0; ks < 2; ks++){
            int kf = ks*32 + lk*8;
            short8 af[4], bf_[4];
            #pragma unroll
            for (int m=0;m<4;m++) af[m] = *(const short8*)&As[wr*64 + m*16 + lr][kf];
            #pragma unroll
            for (int n=0;n<4;n++) bf_[n] = *(const short8*)&Bs[wc*64 + n*16 + lr][kf];
            #pragma unroll
            for (int m=0;m<4;m++)
                #pragma unroll
                for (int n=0;n<4;n++)
                    acc[m][n] = __builtin_amdgcn_mfma_f32_16x16x32_bf16(af[m], bf_[n], acc[m][n], 0,0,0);
        }
        __syncthreads();
    }
    #pragma unroll
    for (int m=0;m<4;m++){
        #pragma unroll
        for (int n=0;n<4;n++){
            int col = col0 + wc*64 + n*16 + lr;
            if (col < N){
                float bb = bias[col];
                #pragma unroll
                for (int j=0;j<4;j++){
                    int row = row0 + wr*64 + m*16 + lk*4 + j;
                    C[(size_t)row*ldc + col] = acc[m][n][j] + bb;
                }
            }
        }
    }
}

// ---------- scan: i=0 ----------
__global__ void k_step0(const float* __restrict__ gi, const float* __restrict__ gh0,
                        const float* __restrict__ h0, float* __restrict__ xf,
                        unsigned short* __restrict__ xb){
    int t = blockIdx.x*blockDim.x + threadIdx.x;
    if (t >= NB*NH) return;
    int b = t >> 9, h = t & 511;
    const float* g = gi + (size_t)b*NS*H3;
    float r = sigmf(g[h] + gh0[h]);
    float z = sigmf(g[512+h] + gh0[512+h]);
    float n = tanhf(g[1024+h] + r*gh0[1024+h]);
    float v = (1.f-z)*n + z*h0[h];
    size_t o = (size_t)b*NS*NH + h;
    xf[o] = v;
    xb[o] = f2bf(v);
}

// ---------- persistent scan: steps 1..127 in one kernel ----------
// 128 wgs = 64 h-slices x 2 batch-halves. wg owns h in [h0,h0+8), b in [b0,b0+32).
// Per step: gh = [hid1;hid2](64 rows) x 24 gate-cols via MFMA (A from global xb,
// B = Whh slice in LDS, staged once), gate fusion, then one device-scope barrier.
__global__ __launch_bounds__(256) void k_scan(const float* __restrict__ gi,
        const unsigned short* __restrict__ Whh, const float* __restrict__ bhh,
        const float* __restrict__ alpha, const int* __restrict__ idx,
        float* __restrict__ xf, unsigned short* __restrict__ xb, int* __restrict__ bar){
    __shared__ unsigned short Ws[32][520];
    __shared__ float ghs[64][36];
    __shared__ float bhs[24];
    __shared__ int rowidx[32];
    int wgid = blockIdx.x;
    int hs = wgid >> 1, bh = wgid & 1;
    int h0 = hs*8, b0 = bh*32;
    int tid = threadIdx.x;

    // stage Whh slice (rows: 0-7 r-gate, 8-15 z, 16-23 n; 24-31 zero pad)
    for (int c = tid; c < 24*64; c += 256){
        int rr = c >> 6, ko = (c & 63)*8;
        int g = rr >> 3, j = rr & 7;
        *(short8*)&Ws[rr][ko] = *(const short8*)(Whh + (size_t)(g*512 + h0 + j)*NH + ko);
    }
    for (int c = tid; c < 8*520; c += 256) Ws[24 + c/520][c%520] = 0;
    if (tid < 24){ int g = tid >> 3, j = tid & 7; bhs[tid] = bhh[g*512 + h0 + j]; }

    int lane = tid & 63, w4 = tid >> 6;
    int lr = lane & 15, lk = lane >> 4;
    int b32m = (w4 & 1)*16 + lr;            // A-row's batch within half
    int var = w4 >> 1;                      // 0: hid1 path, 1: hid2 path
    int bm = b0 + b32m;

    int gb = tid >> 3, gh_ = tid & 7;       // gate phase: b32 = gb, h-off = gh_
    int bg = b0 + gb;
    int hgl = h0 + gh_;

    for (int i = 1; i < NS; i++){
        if (tid < 32) rowidx[tid] = idx[(b0 + tid)*NS + i];
        __syncthreads();
        // ---- matmul: wave w4 owns M-tile w4 (rows w4*16..+15), both N-tiles ----
        int srow = var ? rowidx[b32m] : (i-1);
        const unsigned short* ap = xb + ((size_t)(bm*NS) + srow)*NH + lk*8;
        f32x4 acc0 = {}, acc1 = {};
        #pragma unroll
        for (int ks = 0; ks < 16; ks++){
            short8 a = *(const short8*)(ap + ks*32);
            short8 bf0 = *(const short8*)&Ws[lr][ks*32 + lk*8];
            short8 bf1 = *(const short8*)&Ws[16 + lr][ks*32 + lk*8];
            acc0 = __builtin_amdgcn_mfma_f32_16x16x32_bf16(a, bf0, acc0, 0,0,0);
            acc1 = __builtin_amdgcn_mfma_f32_16x16x32_bf16(a, bf1, acc1, 0,0,0);
        }
        #pragma unroll
        for (int j = 0; j < 4; j++){
            int mrow = w4*16 + lk*4 + j;
            ghs[mrow][lr] = acc0[j];
            ghs[mrow][16 + lr] = acc1[j];
        }
        __syncthreads();
        // ---- gate fusion: 32 b x 8 h = 256 threads ----
        {
            float g1r = ghs[gb][gh_],      g1z = ghs[gb][8+gh_],      g1n = ghs[gb][16+gh_];
            float g2r = ghs[32+gb][gh_],   g2z = ghs[32+gb][8+gh_],   g2n = ghs[32+gb][16+gh_];
            float bhr = bhs[gh_], bhz = bhs[8+gh_], bhn = bhs[16+gh_];
            const float* gir = gi + ((size_t)bg*NS + i)*H3;
            float ir = gir[hgl], iz = gir[512+hgl], inn = gir[1024+hgl];
            float h1p = xf[((size_t)bg*NS + i-1)*NH + hgl];
            float h2p = xf[((size_t)bg*NS + rowidx[gb])*NH + hgl];
            float r1 = sigmf(ir + g1r + bhr), z1 = sigmf(iz + g1z + bhz);
            float n1 = tanhf(inn + r1*(g1n + bhn));
            float hid1 = (1.f-z1)*n1 + z1*h1p;
            float r2 = sigmf(ir + g2r + bhr), z2 = sigmf(iz + g2z + bhz);
            float n2 = tanhf(inn + r2*(g2n + bhn));
            float hid2 = (1.f-z2)*n2 + z2*h2p;
            float a0 = alpha[((size_t)bg*NS+i)*2+0], a1 = alpha[((size_t)bg*NS+i)*2+1];
            float v = a0*hid1 + a1*hid2;
            size_t o = ((size_t)bg*NS + i)*NH + hgl;
            xf[o] = v;
            xb[o] = f2bf(v);
        }
        __syncthreads();
        // ---- device-scope grid barrier (monotonic counter) ----
        if (i < NS-1){
            if (tid == 0){
                __threadfence();
                __hip_atomic_fetch_add(bar, 1, __ATOMIC_RELEASE, __HIP_MEMORY_SCOPE_AGENT);
                int target = NWG_SCAN * i;
                while (__hip_atomic_load(bar, __ATOMIC_RELAXED, __HIP_MEMORY_SCOPE_AGENT) < target)
                    __builtin_amdgcn_s_sleep(1);
                __threadfence();
            }
            __syncthreads();
        }
    }
}

// out_time: wave per row (reads f32 state)
__global__ void k_time(const float* __restrict__ xf, const float* __restrict__ W_time,
                       const float* __restrict__ b_time, float* __restrict__ out){
    int gw = (int)((blockIdx.x*(size_t)blockDim.x + threadIdx.x) >> 6);
    int lane = threadIdx.x & 63;
    if (gw >= NB*NS) return;
    const float* x = xf + (size_t)gw*NH;
    float s = 0.f;
    for (int k=lane;k<NH;k+=64) s += x[k]*W_time[k];
    for (int off=32; off; off>>=1) s += __shfl_down(s, off);
    if (lane == 0) out[gw] = s + b_time[0];
}

extern "C" void kernel_launch(void* const* d_in, const int* in_sizes, int n_in,
                              void* d_out, int out_size, void* d_ws, size_t ws_size,
                              hipStream_t stream){
    const float* src    = (const float*)d_in[0];
    const int*   lens   = (const int*)d_in[1];
    const int*   seq    = (const int*)d_in[2];
    const float* X      = (const float*)d_in[3];
    const float* A      = (const float*)d_in[4];
    const float* W_attn = (const float*)d_in[5];
    const float* a_attn = (const float*)d_in[6];
    const float* W_ih   = (const float*)d_in[7];
    const float* W_hh   = (const float*)d_in[8];
    const float* b_ih   = (const float*)d_in[9];
    const float* b_hh   = (const float*)d_in[10];
    const float* h0     = (const float*)d_in[11];
    const float* W_poi  = (const float*)d_in[12];
    const float* b_poi  = (const float*)d_in[13];
    const float* W_time = (const float*)d_in[14];
    const float* b_time = (const float*)d_in[15];
    const float* W_cat  = (const float*)d_in[16];
    const float* b_cat  = (const float*)d_in[17];

    // ws layout (~36 MB)
    char* ws = (char*)d_ws;
    float*          xf      = (float*)(ws + 0);                 // 16777216
    unsigned short* xb      = (unsigned short*)(ws + 16777216); // 8388608
    unsigned short* Whh_bf  = (unsigned short*)(ws + 25165824); // 1572864
    unsigned short* Wpoi_bf = (unsigned short*)(ws + 26738688); // 8388608
    unsigned short* Wcat_bf = (unsigned short*)(ws + 35127296); // 409600
    double*         wh1     = (double*)(ws + 35536896);         // 65536
    double*         wh2     = (double*)(ws + 35602432);         // 65536
    double*         c1d     = (double*)(ws + 35667968);         // 1024
    double*         c2d     = (double*)(ws + 35668992);         // 1024
    float*          alpha   = (float*)(ws + 35670016);          // 65536
    int*            idx     = (int*)(ws + 35735552);            // 32768
    float*          gh0     = (float*)(ws + 35768320);          // 6144
    int*            bar     = (int*)(ws + 35774464);            // 64

    // scratch inside the out_poi region of d_out (dead before out_poi GEMM runs)
    char* ob = (char*)d_out;
    unsigned short* src_bf = (unsigned short*)(ob + 0);         // 8388608
    unsigned short* Wih_bf = (unsigned short*)(ob + 9437184);   // 1572864
    float*          gi     = (float*)(ob + 16777216);           // 50331648

    float* out_poi  = (float*)d_out;                        // 8192 x 8192
    float* out_time = (float*)d_out + (size_t)8192*8192;    // 8192
    float* out_cat  = out_time + 8192;                      // 8192 x 400

    // conversions + barrier init
    k_zero<<<1, 64, 0, stream>>>(bar);
    k_cvt<<<4096, 256, 0, stream>>>(src, src_bf, NB*NS*NE);
    k_cvt<<<768, 256, 0, stream>>>(W_ih, Wih_bf, H3*NE);
    k_cvt<<<768, 256, 0, stream>>>(W_hh, Whh_bf, H3*NH);
    k_cvt<<<4096, 256, 0, stream>>>(W_poi, Wpoi_bf, NPOI_*NH);
    k_cvt<<<200, 256, 0, stream>>>(W_cat, Wcat_bf, NCAT_*NH);

    // attention path (f64, exact argmax)
    k_prep_c<<<1, 128, 0, stream>>>(W_attn, a_attn, c1d, c2d);
    k_wh<<<32, 256, 0, stream>>>(X, c1d, c2d, wh1, wh2);
    k_gh0<<<6, 256, 0, stream>>>(h0, W_hh, b_hh, gh0);
    k_attn<<<2048, 256, 0, stream>>>(seq, lens, A, wh1, wh2, alpha, idx);

    // gi = src @ W_ih^T + b_ih  (8192 x 1536, K=512)
    k_gemm_bf16<<<dim3(12, 64), 256, 0, stream>>>(src_bf, Wih_bf, b_ih, gi, NB*NS, H3, NE, H3);

    // scan
    k_step0<<<128, 256, 0, stream>>>(gi, gh0, h0, xf, xb);
    k_scan<<<NWG_SCAN, 256, 0, stream>>>(gi, Whh_bf, b_hh, alpha, idx, xf, xb, bar);

    // output projections
    k_gemm_bf16<<<dim3(64, 64), 256, 0, stream>>>(xb, Wpoi_bf, b_poi, out_poi, NB*NS, NPOI_, NH, NPOI_);
    k_gemm_bf16<<<dim3(4, 64), 256, 0, stream>>>(xb, Wcat_bf, b_cat, out_cat, NB*NS, NCAT_, NH, NCAT_);
    k_time<<<2048, 256, 0, stream>>>(xf, W_time, b_time, out_time);
}

// Round 4
// 1194.884 us; speedup vs baseline: 1.6958x; 1.6958x over previous
//
#include <hip/hip_runtime.h>
#include <math.h>

typedef __attribute__((ext_vector_type(8))) short short8;
typedef __attribute__((ext_vector_type(4))) float f32x4;

#define NB 64
#define NS 128
#define NE 512
#define NH 512
#define NPOI_ 8192
#define NCAT_ 400
#define NF_ 128
#define H3 1536
#define NEGV -1000000000.0
#define NWG_SCAN 32

__device__ inline float sigmf(float x){ return 1.0f/(1.0f + expf(-x)); }
__device__ inline unsigned short f2bf(float f){
    unsigned u = __float_as_uint(f);
    unsigned r = (u + 0x7fffu + ((u>>16)&1u)) >> 16;
    return (unsigned short)r;
}

// coherent (device-scope) 16B load: bypass local L1/L2, read at coherence point
#define LD16C(d, p, o) asm volatile("global_load_dwordx4 %0, %1, off offset:" o " sc0 sc1" : "=&v"(d) : "v"(p))

// ---------- f32 -> bf16 conversion (n multiple of 4) ----------
__global__ void k_cvt(const float* __restrict__ in, unsigned short* __restrict__ out, int n){
    int t = blockIdx.x*blockDim.x + threadIdx.x;
    int i = t*4;
    if (i < n){
        float4 v = *(const float4*)(in + i);
        ushort4 o;
        o.x = f2bf(v.x); o.y = f2bf(v.y); o.z = f2bf(v.z); o.w = f2bf(v.w);
        *(ushort4*)(out + i) = o;
    }
}

__global__ void k_zero(int* p){ if (threadIdx.x == 0 && blockIdx.x == 0) *p = 0; }

// ---------- phase 1: attention precompute (f64 for argmax stability) ----------
__global__ void k_prep_c(const float* __restrict__ W_attn, const float* __restrict__ a_attn,
                         double* __restrict__ c1d, double* __restrict__ c2d){
    int f = blockIdx.x*blockDim.x + threadIdx.x;
    if (f < NF_){
        double s1=0.0, s2=0.0;
        for (int k=0;k<NF_;k++){
            double w = (double)W_attn[f*NF_+k];
            s1 += w*(double)a_attn[k];
            s2 += w*(double)a_attn[NF_+k];
        }
        c1d[f]=s1; c2d[f]=s2;
    }
}

__global__ void k_wh(const float* __restrict__ X, const double* __restrict__ c1d,
                     const double* __restrict__ c2d, double* __restrict__ wh1, double* __restrict__ wh2){
    int p = blockIdx.x*blockDim.x + threadIdx.x;
    if (p < NPOI_){
        const float* x = X + (size_t)p*NF_;
        double s1=0.0,s2=0.0;
        for (int k=0;k<NF_;k++){ double xv=(double)x[k]; s1+=xv*c1d[k]; s2+=xv*c2d[k]; }
        wh1[p]=s1; wh2[p]=s2;
    }
}

__global__ void k_gh0(const float* __restrict__ h0, const float* __restrict__ W_hh,
                      const float* __restrict__ b_hh, float* __restrict__ gh0){
    int c = blockIdx.x*blockDim.x + threadIdx.x;
    if (c < H3){
        const float* w = W_hh + (size_t)c*NH;
        float s=0.f;
        for (int k=0;k<NH;k++) s += h0[k]*w[k];
        gh0[c] = s + b_hh[c];
    }
}

__device__ inline double shfl_down_d(double x, int off){
    long long v = __double_as_longlong(x);
    int lo = (int)(v & 0xffffffffLL), hi = (int)(((unsigned long long)v)>>32);
    lo = __shfl_down(lo, off); hi = __shfl_down(hi, off);
    return __longlong_as_double(((long long)hi<<32) | (unsigned long long)(unsigned int)lo);
}

__global__ void k_attn(const int* __restrict__ seq, const int* __restrict__ lens,
                       const float* __restrict__ A, const double* __restrict__ wh1,
                       const double* __restrict__ wh2, float* __restrict__ alpha,
                       int* __restrict__ idxout){
    int gw = (int)((blockIdx.x*(size_t)blockDim.x + threadIdx.x) >> 6);
    int lane = threadIdx.x & 63;
    if (gw >= NB*NS) return;
    int b = gw >> 7, j = gw & 127;
    int len = lens[b];
    int q = seq[b*NS + j];
    double wq = wh2[q];
    bool jvalid = (j < len);
    double mval = -1.0e300; int mk = 0;
    for (int k0=0;k0<NS;k0+=64){
        int k = k0 + lane;
        double val = NEGV;
        if (k < j && jvalid){
            int p = seq[b*NS + k];
            double e = wh1[p] + wq;
            e = (e > 0.0) ? e : 0.2*e;
            val = e * ((double)A[(size_t)p*NPOI_ + q] + 1.0);
        }
        if (val > mval){ mval = val; mk = k; }
    }
    for (int off=32; off; off>>=1){
        double ov = shfl_down_d(mval, off);
        int ok = __shfl_down(mk, off);
        if (ov > mval || (ov == mval && ok < mk)){ mval = ov; mk = ok; }
    }
    if (lane == 0){
        double v0 = mval;
        double v1;
        if (j == 0) v1 = 0.0;
        else if (!jvalid) v1 = NEGV;
        else {
            int p = seq[b*NS + j - 1];
            double e = wh1[p] + wq;
            e = (e > 0.0) ? e : 0.2*e;
            v1 = e * ((double)A[(size_t)p*NPOI_ + q] + 1.0);
        }
        double m = fmax(v0, v1);
        double e0 = exp(v0 - m), e1 = exp(v1 - m);
        double den = e0 + e1;
        alpha[(size_t)(b*NS+j)*2 + 0] = (float)(e0/den);
        alpha[(size_t)(b*NS+j)*2 + 1] = (float)(e1/den);
        idxout[b*NS + j] = mk;
    }
}

// ---------- bf16 MFMA NT GEMM: C[r,c] = sum_k A[r,k]*B[c,k] + bias[c] ----------
#define LDT 88
__global__ __launch_bounds__(256) void k_gemm_bf16(const unsigned short* __restrict__ A,
        const unsigned short* __restrict__ B, const float* __restrict__ bias,
        float* __restrict__ C, int M, int N, int K, int ldc){
    __shared__ unsigned short As[128][LDT];
    __shared__ unsigned short Bs[128][LDT];
    int row0 = blockIdx.y*128, col0 = blockIdx.x*128;
    int tid = threadIdx.x;
    int lane = tid & 63, w = tid >> 6;
    int wr = w >> 1, wc = w & 1;
    int lr = lane & 15, lk = lane >> 4;
    f32x4 acc[4][4] = {};
    for (int k0 = 0; k0 < K; k0 += 64){
        #pragma unroll
        for (int q = 0; q < 4; q++){
            int c = tid + 256*q;
            int r = c >> 3, ko = (c & 7)*8;
            *(short8*)&As[r][ko] = *(const short8*)(A + (size_t)(row0+r)*K + k0 + ko);
            int gc = col0 + r;
            short8 bv = {};
            if (gc < N) bv = *(const short8*)(B + (size_t)gc*K + k0 + ko);
            *(short8*)&Bs[r][ko] = bv;
        }
        __syncthreads();
        #pragma unroll
        for (int ks = 0; ks < 2; ks++){
            int kf = ks*32 + lk*8;
            short8 af[4], bf_[4];
            #pragma unroll
            for (int m=0;m<4;m++) af[m] = *(const short8*)&As[wr*64 + m*16 + lr][kf];
            #pragma unroll
            for (int n=0;n<4;n++) bf_[n] = *(const short8*)&Bs[wc*64 + n*16 + lr][kf];
            #pragma unroll
            for (int m=0;m<4;m++)
                #pragma unroll
                for (int n=0;n<4;n++)
                    acc[m][n] = __builtin_amdgcn_mfma_f32_16x16x32_bf16(af[m], bf_[n], acc[m][n], 0,0,0);
        }
        __syncthreads();
    }
    #pragma unroll
    for (int m=0;m<4;m++){
        #pragma unroll
        for (int n=0;n<4;n++){
            int col = col0 + wc*64 + n*16 + lr;
            if (col < N){
                float bb = bias[col];
                #pragma unroll
                for (int j=0;j<4;j++){
                    int row = row0 + wr*64 + m*16 + lk*4 + j;
                    C[(size_t)row*ldc + col] = acc[m][n][j] + bb;
                }
            }
        }
    }
}

// ---------- scan: i=0 ----------
__global__ void k_step0(const float* __restrict__ gi, const float* __restrict__ gh0,
                        const float* __restrict__ h0, float* __restrict__ xf,
                        unsigned short* __restrict__ xb){
    int t = blockIdx.x*blockDim.x + threadIdx.x;
    if (t >= NB*NH) return;
    int b = t >> 9, h = t & 511;
    const float* g = gi + (size_t)b*NS*H3;
    float r = sigmf(g[h] + gh0[h]);
    float z = sigmf(g[512+h] + gh0[512+h]);
    float n = tanhf(g[1024+h] + r*gh0[1024+h]);
    float v = (1.f-z)*n + z*h0[h];
    size_t o = (size_t)b*NS*NH + h;
    xf[o] = v;
    xb[o] = f2bf(v);
}

// ---------- persistent scan v2: 32 wgs x 512 thr, W in registers, coherent state path ----------
// wg g owns h-slice [g*16, g*16+16): N-cols {gate*512 + g*16 + j}. All 64 batches.
// wave w (0..7): khalf = w&1, mgrp = w>>1. M rows 0-63 = hid1(b), 64-127 = hid2(b).
// Per wave: B-frags (3 gates x 8 ks) resident in VGPRs; per step 16 coherent A-loads,
// 48 MFMA, partial-K sums to LDS, gate fusion, sc1 state write, 32-wg barrier (no fences).
__global__ __launch_bounds__(512, 2) void k_scan(const float* __restrict__ gi,
        const unsigned short* __restrict__ Whh, const float* __restrict__ bhh,
        const float* __restrict__ alpha, const int* __restrict__ idx,
        float* __restrict__ xf, unsigned short* __restrict__ xb, int* __restrict__ bar){
    __shared__ float ghs[2][128][50];
    __shared__ int rowidx[64];
    __shared__ float bhs[48];
    const int g = blockIdx.x;
    const int tid = threadIdx.x;
    const int lane = tid & 63, w = tid >> 6;
    const int kh = w & 1, mgrp = w >> 1;
    const int lr = lane & 15, lk = lane >> 4;

    // resident B-fragments: W rows gate*512 + g*16 + lr, k-chunk kh*256 + ks*32 + lk*8
    short8 bw0[8], bw1[8], bw2[8];
    {
        const unsigned short* wb = Whh + ((size_t)(g*16 + lr))*NH + kh*256 + lk*8;
        #pragma unroll
        for (int ks=0; ks<8; ks++){
            bw0[ks] = *(const short8*)(wb + 0*262144 + ks*32);
            bw1[ks] = *(const short8*)(wb + 1*262144 + ks*32);
            bw2[ks] = *(const short8*)(wb + 2*262144 + ks*32);
        }
    }
    if (tid < 48) bhs[tid] = bhh[(tid>>4)*512 + g*16 + (tid&15)];

    const int gb = tid >> 3, hp = tid & 7;      // gate phase: batch gb, h-pair hp
    const int hg = g*16 + hp*2;

    for (int i = 1; i < NS; i++){
        if (tid < 64) rowidx[tid] = idx[tid*NS + i];
        __syncthreads();
        // gate-operand prefetch (normal cached loads; latency hidden under MFMA)
        float2 giv0 = *(const float2*)(gi + ((size_t)gb*NS + i)*H3 + hg);
        float2 giv1 = *(const float2*)(gi + ((size_t)gb*NS + i)*H3 + 512 + hg);
        float2 giv2 = *(const float2*)(gi + ((size_t)gb*NS + i)*H3 + 1024 + hg);
        float2 alv  = *(const float2*)(alpha + ((size_t)gb*NS + i)*2);
        float2 h1p  = *(const float2*)(xf + ((size_t)gb*NS + (i-1))*NH + hg);
        float2 h2p  = *(const float2*)(xf + ((size_t)gb*NS + rowidx[gb])*NH + hg);
        // coherent A-loads: 2 M-tiles x 8 k-chunks
        int r0 = mgrp*32 + lr, r1 = r0 + 16;
        int ab0 = r0 & 63, ab1 = r1 & 63;
        int s0 = (r0 >> 6) ? rowidx[ab0] : (i-1);
        int s1 = (r1 >> 6) ? rowidx[ab1] : (i-1);
        const unsigned short* ap0 = xb + ((size_t)ab0*NS + s0)*NH + kh*256 + lk*8;
        const unsigned short* ap1 = xb + ((size_t)ab1*NS + s1)*NH + kh*256 + lk*8;
        short8 a0[8], a1[8];
        LD16C(a0[0], ap0, "0");   LD16C(a0[1], ap0, "64");  LD16C(a0[2], ap0, "128"); LD16C(a0[3], ap0, "192");
        LD16C(a0[4], ap0, "256"); LD16C(a0[5], ap0, "320"); LD16C(a0[6], ap0, "384"); LD16C(a0[7], ap0, "448");
        LD16C(a1[0], ap1, "0");   LD16C(a1[1], ap1, "64");  LD16C(a1[2], ap1, "128"); LD16C(a1[3], ap1, "192");
        LD16C(a1[4], ap1, "256"); LD16C(a1[5], ap1, "320"); LD16C(a1[6], ap1, "384"); LD16C(a1[7], ap1, "448");
        asm volatile("s_waitcnt vmcnt(0)" ::: "memory");
        __builtin_amdgcn_sched_barrier(0);
        f32x4 acc00 = {}, acc01 = {}, acc02 = {}, acc10 = {}, acc11 = {}, acc12 = {};
        #pragma unroll
        for (int ks=0; ks<8; ks++){
            acc00 = __builtin_amdgcn_mfma_f32_16x16x32_bf16(a0[ks], bw0[ks], acc00, 0,0,0);
            acc01 = __builtin_amdgcn_mfma_f32_16x16x32_bf16(a0[ks], bw1[ks], acc01, 0,0,0);
            acc02 = __builtin_amdgcn_mfma_f32_16x16x32_bf16(a0[ks], bw2[ks], acc02, 0,0,0);
            acc10 = __builtin_amdgcn_mfma_f32_16x16x32_bf16(a1[ks], bw0[ks], acc10, 0,0,0);
            acc11 = __builtin_amdgcn_mfma_f32_16x16x32_bf16(a1[ks], bw1[ks], acc11, 0,0,0);
            acc12 = __builtin_amdgcn_mfma_f32_16x16x32_bf16(a1[ks], bw2[ks], acc12, 0,0,0);
        }
        #pragma unroll
        for (int j=0;j<4;j++){
            int m0 = mgrp*32 + lk*4 + j, m1 = m0 + 16;
            ghs[kh][m0][lr]    = acc00[j];
            ghs[kh][m0][16+lr] = acc01[j];
            ghs[kh][m0][32+lr] = acc02[j];
            ghs[kh][m1][lr]    = acc10[j];
            ghs[kh][m1][16+lr] = acc11[j];
            ghs[kh][m1][32+lr] = acc12[j];
        }
        __syncthreads();
        // ---- gate fusion: thread -> (batch gb, h pair hg, hg+1) ----
        float o0, o1;
        {
            float ir, iz, inn, hh1, hh2;
            #pragma unroll
            for (int u=0; u<2; u++){
                int hl = hp*2 + u;
                float g1r = ghs[0][gb][hl]       + ghs[1][gb][hl]       + bhs[hl];
                float g1z = ghs[0][gb][16+hl]    + ghs[1][gb][16+hl]    + bhs[16+hl];
                float g1n = ghs[0][gb][32+hl]    + ghs[1][gb][32+hl]    + bhs[32+hl];
                float g2r = ghs[0][64+gb][hl]    + ghs[1][64+gb][hl]    + bhs[hl];
                float g2z = ghs[0][64+gb][16+hl] + ghs[1][64+gb][16+hl] + bhs[16+hl];
                float g2n = ghs[0][64+gb][32+hl] + ghs[1][64+gb][32+hl] + bhs[32+hl];
                ir  = u ? giv0.y : giv0.x;
                iz  = u ? giv1.y : giv1.x;
                inn = u ? giv2.y : giv2.x;
                hh1 = u ? h1p.y : h1p.x;
                hh2 = u ? h2p.y : h2p.x;
                float r1v = sigmf(ir + g1r), z1 = sigmf(iz + g1z);
                float n1 = tanhf(inn + r1v*g1n);
                float hid1 = (1.f-z1)*n1 + z1*hh1;
                float r2v = sigmf(ir + g2r), z2 = sigmf(iz + g2z);
                float n2 = tanhf(inn + r2v*g2n);
                float hid2 = (1.f-z2)*n2 + z2*hh2;
                float v = alv.x*hid1 + alv.y*hid2;
                if (u) o1 = v; else o0 = v;
            }
        }
        *(float2*)(xf + ((size_t)gb*NS + i)*NH + hg) = make_float2(o0, o1);
        unsigned pk = (unsigned)f2bf(o0) | ((unsigned)f2bf(o1) << 16);
        __hip_atomic_store((unsigned*)(xb + ((size_t)gb*NS + i)*NH + hg), pk,
                           __ATOMIC_RELAXED, __HIP_MEMORY_SCOPE_AGENT);
        __syncthreads();   // drains all waves' stores (compiler emits vmcnt(0) before s_barrier)
        if (i < NS-1){
            if (tid == 0){
                __hip_atomic_fetch_add(bar, 1, __ATOMIC_RELAXED, __HIP_MEMORY_SCOPE_AGENT);
                int target = NWG_SCAN * i;
                while (__hip_atomic_load(bar, __ATOMIC_RELAXED, __HIP_MEMORY_SCOPE_AGENT) < target)
                    __builtin_amdgcn_s_sleep(2);
            }
            __syncthreads();
        }
    }
}

// out_time: wave per row (reads f32 state)
__global__ void k_time(const float* __restrict__ xf, const float* __restrict__ W_time,
                       const float* __restrict__ b_time, float* __restrict__ out){
    int gw = (int)((blockIdx.x*(size_t)blockDim.x + threadIdx.x) >> 6);
    int lane = threadIdx.x & 63;
    if (gw >= NB*NS) return;
    const float* x = xf + (size_t)gw*NH;
    float s = 0.f;
    for (int k=lane;k<NH;k+=64) s += x[k]*W_time[k];
    for (int off=32; off; off>>=1) s += __shfl_down(s, off);
    if (lane == 0) out[gw] = s + b_time[0];
}

extern "C" void kernel_launch(void* const* d_in, const int* in_sizes, int n_in,
                              void* d_out, int out_size, void* d_ws, size_t ws_size,
                              hipStream_t stream){
    const float* src    = (const float*)d_in[0];
    const int*   lens   = (const int*)d_in[1];
    const int*   seq    = (const int*)d_in[2];
    const float* X      = (const float*)d_in[3];
    const float* A      = (const float*)d_in[4];
    const float* W_attn = (const float*)d_in[5];
    const float* a_attn = (const float*)d_in[6];
    const float* W_ih   = (const float*)d_in[7];
    const float* W_hh   = (const float*)d_in[8];
    const float* b_ih   = (const float*)d_in[9];
    const float* b_hh   = (const float*)d_in[10];
    const float* h0     = (const float*)d_in[11];
    const float* W_poi  = (const float*)d_in[12];
    const float* b_poi  = (const float*)d_in[13];
    const float* W_time = (const float*)d_in[14];
    const float* b_time = (const float*)d_in[15];
    const float* W_cat  = (const float*)d_in[16];
    const float* b_cat  = (const float*)d_in[17];

    // ws layout (~36 MB)
    char* ws = (char*)d_ws;
    float*          xf      = (float*)(ws + 0);                 // 16777216
    unsigned short* xb      = (unsigned short*)(ws + 16777216); // 8388608
    unsigned short* Whh_bf  = (unsigned short*)(ws + 25165824); // 1572864
    unsigned short* Wpoi_bf = (unsigned short*)(ws + 26738688); // 8388608
    unsigned short* Wcat_bf = (unsigned short*)(ws + 35127296); // 409600
    double*         wh1     = (double*)(ws + 35536896);         // 65536
    double*         wh2     = (double*)(ws + 35602432);         // 65536
    double*         c1d     = (double*)(ws + 35667968);         // 1024
    double*         c2d     = (double*)(ws + 35668992);         // 1024
    float*          alpha   = (float*)(ws + 35670016);          // 65536
    int*            idx     = (int*)(ws + 35735552);            // 32768
    float*          gh0     = (float*)(ws + 35768320);          // 6144
    int*            bar     = (int*)(ws + 35774464);            // 64

    // scratch inside the out_poi region of d_out (dead before out_poi GEMM runs)
    char* ob = (char*)d_out;
    unsigned short* src_bf = (unsigned short*)(ob + 0);         // 8388608
    unsigned short* Wih_bf = (unsigned short*)(ob + 9437184);   // 1572864
    float*          gi     = (float*)(ob + 16777216);           // 50331648

    float* out_poi  = (float*)d_out;                        // 8192 x 8192
    float* out_time = (float*)d_out + (size_t)8192*8192;    // 8192
    float* out_cat  = out_time + 8192;                      // 8192 x 400

    // conversions + barrier init
    k_zero<<<1, 64, 0, stream>>>(bar);
    k_cvt<<<4096, 256, 0, stream>>>(src, src_bf, NB*NS*NE);
    k_cvt<<<768, 256, 0, stream>>>(W_ih, Wih_bf, H3*NE);
    k_cvt<<<768, 256, 0, stream>>>(W_hh, Whh_bf, H3*NH);
    k_cvt<<<4096, 256, 0, stream>>>(W_poi, Wpoi_bf, NPOI_*NH);
    k_cvt<<<200, 256, 0, stream>>>(W_cat, Wcat_bf, NCAT_*NH);

    // attention path (f64, exact argmax)
    k_prep_c<<<1, 128, 0, stream>>>(W_attn, a_attn, c1d, c2d);
    k_wh<<<32, 256, 0, stream>>>(X, c1d, c2d, wh1, wh2);
    k_gh0<<<6, 256, 0, stream>>>(h0, W_hh, b_hh, gh0);
    k_attn<<<2048, 256, 0, stream>>>(seq, lens, A, wh1, wh2, alpha, idx);

    // gi = src @ W_ih^T + b_ih  (8192 x 1536, K=512)
    k_gemm_bf16<<<dim3(12, 64), 256, 0, stream>>>(src_bf, Wih_bf, b_ih, gi, NB*NS, H3, NE, H3);

    // scan
    k_step0<<<128, 256, 0, stream>>>(gi, gh0, h0, xf, xb);
    k_scan<<<NWG_SCAN, 512, 0, stream>>>(gi, Whh_bf, b_hh, alpha, idx, xf, xb, bar);

    // output projections
    k_gemm_bf16<<<dim3(64, 64), 256, 0, stream>>>(xb, Wpoi_bf, b_poi, out_poi, NB*NS, NPOI_, NH, NPOI_);
    k_gemm_bf16<<<dim3(4, 64), 256, 0, stream>>>(xb, Wcat_bf, b_cat, out_cat, NB*NS, NCAT_, NH, NCAT_);
    k_time<<<2048, 256, 0, stream>>>(xf, W_time, b_time, out_time);
}

// Round 7
// 1127.641 us; speedup vs baseline: 1.7969x; 1.0596x over previous
//
#include <hip/hip_runtime.h>
#include <math.h>

typedef __attribute__((ext_vector_type(8))) short short8;
typedef __attribute__((ext_vector_type(4))) float f32x4;

#define NB 64
#define NS 128
#define NE 512
#define NH 512
#define NPOI_ 8192
#define NCAT_ 400
#define NF_ 128
#define H3 1536
#define NEGV -1000000000.0
#define GSZ 32
#define NWG_LAUNCH 256

__device__ inline float sigmf(float x){ return 1.0f/(1.0f + expf(-x)); }
__device__ inline unsigned short f2bf(float f){
    unsigned u = __float_as_uint(f);
    unsigned r = (u + 0x7fffu + ((u>>16)&1u)) >> 16;
    return (unsigned short)r;
}

// XCD-L2-local 16B load (sc0: bypass L1, read this XCD's L2)
#define LD16C(d, p, o) asm volatile("global_load_dwordx4 %0, %1, off offset:" o " sc0" : "=&v"(d) : "v"(p))

// ---------- f32 -> bf16 conversion (n multiple of 4) ----------
__global__ void k_cvt(const float* __restrict__ in, unsigned short* __restrict__ out, int n){
    int t = blockIdx.x*blockDim.x + threadIdx.x;
    int i = t*4;
    if (i < n){
        float4 v = *(const float4*)(in + i);
        ushort4 o;
        o.x = f2bf(v.x); o.y = f2bf(v.y); o.z = f2bf(v.z); o.w = f2bf(v.w);
        *(ushort4*)(out + i) = o;
    }
}

__global__ void k_zero(int* p){ int t = threadIdx.x; if (t < 320) p[t] = 0; }

// ---------- phase 1: attention precompute (f64 for argmax stability) ----------
__global__ void k_prep_c(const float* __restrict__ W_attn, const float* __restrict__ a_attn,
                         double* __restrict__ c1d, double* __restrict__ c2d){
    int f = blockIdx.x*blockDim.x + threadIdx.x;
    if (f < NF_){
        double s1=0.0, s2=0.0;
        for (int k=0;k<NF_;k++){
            double w = (double)W_attn[f*NF_+k];
            s1 += w*(double)a_attn[k];
            s2 += w*(double)a_attn[NF_+k];
        }
        c1d[f]=s1; c2d[f]=s2;
    }
}

__global__ void k_wh(const float* __restrict__ X, const double* __restrict__ c1d,
                     const double* __restrict__ c2d, double* __restrict__ wh1, double* __restrict__ wh2){
    int p = blockIdx.x*blockDim.x + threadIdx.x;
    if (p < NPOI_){
        const float* x = X + (size_t)p*NF_;
        double s1=0.0,s2=0.0;
        for (int k=0;k<NF_;k++){ double xv=(double)x[k]; s1+=xv*c1d[k]; s2+=xv*c2d[k]; }
        wh1[p]=s1; wh2[p]=s2;
    }
}

__global__ void k_gh0(const float* __restrict__ h0, const float* __restrict__ W_hh,
                      const float* __restrict__ b_hh, float* __restrict__ gh0){
    int c = blockIdx.x*blockDim.x + threadIdx.x;
    if (c < H3){
        const float* w = W_hh + (size_t)c*NH;
        float s=0.f;
        for (int k=0;k<NH;k++) s += h0[k]*w[k];
        gh0[c] = s + b_hh[c];
    }
}

__device__ inline double shfl_down_d(double x, int off){
    long long v = __double_as_longlong(x);
    int lo = (int)(v & 0xffffffffLL), hi = (int)(((unsigned long long)v)>>32);
    lo = __shfl_down(lo, off); hi = __shfl_down(hi, off);
    return __longlong_as_double(((long long)hi<<32) | (unsigned long long)(unsigned int)lo);
}

__global__ void k_attn(const int* __restrict__ seq, const int* __restrict__ lens,
                       const float* __restrict__ A, const double* __restrict__ wh1,
                       const double* __restrict__ wh2, float* __restrict__ alpha,
                       int* __restrict__ idxout){
    int gw = (int)((blockIdx.x*(size_t)blockDim.x + threadIdx.x) >> 6);
    int lane = threadIdx.x & 63;
    if (gw >= NB*NS) return;
    int b = gw >> 7, j = gw & 127;
    int len = lens[b];
    int q = seq[b*NS + j];
    double wq = wh2[q];
    bool jvalid = (j < len);
    double mval = -1.0e300; int mk = 0;
    for (int k0=0;k0<NS;k0+=64){
        int k = k0 + lane;
        double val = NEGV;
        if (k < j && jvalid){
            int p = seq[b*NS + k];
            double e = wh1[p] + wq;
            e = (e > 0.0) ? e : 0.2*e;
            val = e * ((double)A[(size_t)p*NPOI_ + q] + 1.0);
        }
        if (val > mval){ mval = val; mk = k; }
    }
    for (int off=32; off; off>>=1){
        double ov = shfl_down_d(mval, off);
        int ok = __shfl_down(mk, off);
        if (ov > mval || (ov == mval && ok < mk)){ mval = ov; mk = ok; }
    }
    if (lane == 0){
        double v0 = mval;
        double v1;
        if (j == 0) v1 = 0.0;
        else if (!jvalid) v1 = NEGV;
        else {
            int p = seq[b*NS + j - 1];
            double e = wh1[p] + wq;
            e = (e > 0.0) ? e : 0.2*e;
            v1 = e * ((double)A[(size_t)p*NPOI_ + q] + 1.0);
        }
        double m = fmax(v0, v1);
        double e0 = exp(v0 - m), e1 = exp(v1 - m);
        double den = e0 + e1;
        alpha[(size_t)(b*NS+j)*2 + 0] = (float)(e0/den);
        alpha[(size_t)(b*NS+j)*2 + 1] = (float)(e1/den);
        idxout[b*NS + j] = mk;
    }
}

// ---------- bf16 MFMA NT GEMM: C[r,c] = sum_k A[r,k]*B[c,k] + bias[c] ----------
#define LDT 88
__global__ __launch_bounds__(256) void k_gemm_bf16(const unsigned short* __restrict__ A,
        const unsigned short* __restrict__ B, const float* __restrict__ bias,
        float* __restrict__ C, int M, int N, int K, int ldc){
    __shared__ unsigned short As[128][LDT];
    __shared__ unsigned short Bs[128][LDT];
    int row0 = blockIdx.y*128, col0 = blockIdx.x*128;
    int tid = threadIdx.x;
    int lane = tid & 63, w = tid >> 6;
    int wr = w >> 1, wc = w & 1;
    int lr = lane & 15, lk = lane >> 4;
    f32x4 acc[4][4] = {};
    for (int k0 = 0; k0 < K; k0 += 64){
        #pragma unroll
        for (int q = 0; q < 4; q++){
            int c = tid + 256*q;
            int r = c >> 3, ko = (c & 7)*8;
            *(short8*)&As[r][ko] = *(const short8*)(A + (size_t)(row0+r)*K + k0 + ko);
            int gc = col0 + r;
            short8 bv = {};
            if (gc < N) bv = *(const short8*)(B + (size_t)gc*K + k0 + ko);
            *(short8*)&Bs[r][ko] = bv;
        }
        __syncthreads();
        #pragma unroll
        for (int ks = 0; ks < 2; ks++){
            int kf = ks*32 + lk*8;
            short8 af[4], bf_[4];
            #pragma unroll
            for (int m=0;m<4;m++) af[m] = *(const short8*)&As[wr*64 + m*16 + lr][kf];
            #pragma unroll
            for (int n=0;n<4;n++) bf_[n] = *(const short8*)&Bs[wc*64 + n*16 + lr][kf];
            #pragma unroll
            for (int m=0;m<4;m++)
                #pragma unroll
                for (int n=0;n<4;n++)
                    acc[m][n] = __builtin_amdgcn_mfma_f32_16x16x32_bf16(af[m], bf_[n], acc[m][n], 0,0,0);
        }
        __syncthreads();
    }
    #pragma unroll
    for (int m=0;m<4;m++){
        #pragma unroll
        for (int n=0;n<4;n++){
            int col = col0 + wc*64 + n*16 + lr;
            if (col < N){
                float bb = bias[col];
                #pragma unroll
                for (int j=0;j<4;j++){
                    int row = row0 + wr*64 + m*16 + lk*4 + j;
                    C[(size_t)row*ldc + col] = acc[m][n][j] + bb;
                }
            }
        }
    }
}

// ---------- scan: i=0 ----------
__global__ void k_step0(const float* __restrict__ gi, const float* __restrict__ gh0,
                        const float* __restrict__ h0, float* __restrict__ xf,
                        unsigned short* __restrict__ xb){
    int t = blockIdx.x*blockDim.x + threadIdx.x;
    if (t >= NB*NH) return;
    int b = t >> 9, h = t & 511;
    const float* g = gi + (size_t)b*NS*H3;
    float r = sigmf(g[h] + gh0[h]);
    float z = sigmf(g[512+h] + gh0[512+h]);
    float n = tanhf(g[1024+h] + r*gh0[1024+h]);
    float v = (1.f-z)*n + z*h0[h];
    size_t o = (size_t)b*NS*NH + h;
    xf[o] = v;
    xb[o] = f2bf(v);
}

// ---------- persistent scan v4: XCD-local groups, W in registers ----------
// Data path (xb loads/stores) is sc0 => stays in the group's XCD L2.
// Step barrier is AGENT-scope atomics (executed at LLC; polls are coherent
// loads) -- the r4-proven pattern; r6's sc0-polled barrier deadlocked because
// memory-side atomics don't update clean L2 copies of the counter line.
__global__ __launch_bounds__(512, 2) void k_scan(const float* __restrict__ gi,
        const unsigned short* __restrict__ Whh, const float* __restrict__ bhh,
        const float* __restrict__ alpha, const int* __restrict__ idx,
        float* __restrict__ xf, unsigned short* __restrict__ xb, int* __restrict__ ctrl){
    __shared__ float ghs[2][128][50];
    __shared__ unsigned char idx8[NB*NS];
    __shared__ float bhs[48];
    __shared__ int s_go, s_rank, s_xcd;
    const int tid = threadIdx.x;

    // ---- election (tid 0) ----
    if (tid == 0){
        int x;
        asm volatile("s_getreg_b32 %0, hwreg(HW_REG_XCC_ID)" : "=s"(x));
        x &= 7;
        int r = __hip_atomic_fetch_add(&ctrl[x], 1, __ATOMIC_RELAXED, __HIP_MEMORY_SCOPE_AGENT);
        __hip_atomic_fetch_add(&ctrl[8], 1, __ATOMIC_RELAXED, __HIP_MEMORY_SCOPE_AGENT);
        int go = 0;
        if (r < GSZ){
            int spins = 0;
            while (1){
                if (__hip_atomic_load(&ctrl[x], __ATOMIC_RELAXED, __HIP_MEMORY_SCOPE_AGENT) >= GSZ){ go = 1; break; }
                if (__hip_atomic_load(&ctrl[8], __ATOMIC_RELAXED, __HIP_MEMORY_SCOPE_AGENT) >= NWG_LAUNCH
                    || spins > (1<<20)){
                    go = (__hip_atomic_load(&ctrl[x], __ATOMIC_RELAXED, __HIP_MEMORY_SCOPE_AGENT) >= GSZ);
                    break;
                }
                spins++;
                __builtin_amdgcn_s_sleep(1);
            }
        }
        s_go = go; s_rank = r; s_xcd = x;
    }
    __syncthreads();
    if (!s_go) return;
    const int g = s_rank;                      // h-slice [g*16, g*16+16)
    int* const barp = ctrl + 64 + s_xcd*32;    // per-XCD barrier line

    // ---- one-time staging ----
    const int lane = tid & 63, w = tid >> 6;
    const int kh = w & 1, mgrp = w >> 1;
    const int lr = lane & 15, lk = lane >> 4;

    short8 bw0[8], bw1[8], bw2[8];
    {
        const unsigned short* wb = Whh + ((size_t)(g*16 + lr))*NH + kh*256 + lk*8;
        #pragma unroll
        for (int ks=0; ks<8; ks++){
            bw0[ks] = *(const short8*)(wb + 0*262144 + ks*32);
            bw1[ks] = *(const short8*)(wb + 1*262144 + ks*32);
            bw2[ks] = *(const short8*)(wb + 2*262144 + ks*32);
        }
    }
    if (tid < 48) bhs[tid] = bhh[(tid>>4)*512 + g*16 + (tid&15)];
    for (int c = tid; c < NB*NS; c += 512) idx8[c] = (unsigned char)idx[c];

    const int gb = tid >> 3, hp = tid & 7;     // gate phase: batch gb, h-pair hp
    const int hg = g*16 + hp*2;

    const int r0 = mgrp*32 + lr, r1 = r0 + 16;
    const int ab0 = r0 & 63, ab1 = r1 & 63;
    const int v0_ = r0 >> 6, v1_ = r1 >> 6;

    float2 h1prev = *(const float2*)(xf + ((size_t)gb*NS)*NH + hg);
    float2 nx0 = *(const float2*)(gi + ((size_t)gb*NS + 1)*H3 + hg);
    float2 nx1 = *(const float2*)(gi + ((size_t)gb*NS + 1)*H3 + 512 + hg);
    float2 nx2 = *(const float2*)(gi + ((size_t)gb*NS + 1)*H3 + 1024 + hg);
    float2 nxA = *(const float2*)(alpha + ((size_t)gb*NS + 1)*2);
    __syncthreads();

    for (int i = 1; i < NS; i++){
        float2 cg0 = nx0, cg1 = nx1, cg2 = nx2, cA = nxA;
        // ---- A-loads (XCD-L2-local) ----
        int s0 = v0_ ? (int)idx8[ab0*NS + i] : (i-1);
        int s1 = v1_ ? (int)idx8[ab1*NS + i] : (i-1);
        const unsigned short* ap0 = xb + ((size_t)ab0*NS + s0)*NH + kh*256 + lk*8;
        const unsigned short* ap1 = xb + ((size_t)ab1*NS + s1)*NH + kh*256 + lk*8;
        short8 a0[8], a1[8];
        LD16C(a0[0], ap0, "0");   LD16C(a0[1], ap0, "64");  LD16C(a0[2], ap0, "128"); LD16C(a0[3], ap0, "192");
        LD16C(a0[4], ap0, "256"); LD16C(a0[5], ap0, "320"); LD16C(a0[6], ap0, "384"); LD16C(a0[7], ap0, "448");
        LD16C(a1[0], ap1, "0");   LD16C(a1[1], ap1, "64");  LD16C(a1[2], ap1, "128"); LD16C(a1[3], ap1, "192");
        LD16C(a1[4], ap1, "256"); LD16C(a1[5], ap1, "320"); LD16C(a1[6], ap1, "384"); LD16C(a1[7], ap1, "448");
        asm volatile("s_waitcnt vmcnt(0)" ::: "memory");
        __builtin_amdgcn_sched_barrier(0);
        f32x4 acc00 = {}, acc01 = {}, acc02 = {}, acc10 = {}, acc11 = {}, acc12 = {};
        #pragma unroll
        for (int ks=0; ks<8; ks++){
            acc00 = __builtin_amdgcn_mfma_f32_16x16x32_bf16(a0[ks], bw0[ks], acc00, 0,0,0);
            acc01 = __builtin_amdgcn_mfma_f32_16x16x32_bf16(a0[ks], bw1[ks], acc01, 0,0,0);
            acc02 = __builtin_amdgcn_mfma_f32_16x16x32_bf16(a0[ks], bw2[ks], acc02, 0,0,0);
            acc10 = __builtin_amdgcn_mfma_f32_16x16x32_bf16(a1[ks], bw0[ks], acc10, 0,0,0);
            acc11 = __builtin_amdgcn_mfma_f32_16x16x32_bf16(a1[ks], bw1[ks], acc11, 0,0,0);
            acc12 = __builtin_amdgcn_mfma_f32_16x16x32_bf16(a1[ks], bw2[ks], acc12, 0,0,0);
        }
        // prefetch next step's static operands (off critical path)
        {
            int ip = (i+1 < NS) ? (i+1) : (NS-1);
            nx0 = *(const float2*)(gi + ((size_t)gb*NS + ip)*H3 + hg);
            nx1 = *(const float2*)(gi + ((size_t)gb*NS + ip)*H3 + 512 + hg);
            nx2 = *(const float2*)(gi + ((size_t)gb*NS + ip)*H3 + 1024 + hg);
            nxA = *(const float2*)(alpha + ((size_t)gb*NS + ip)*2);
        }
        #pragma unroll
        for (int j=0;j<4;j++){
            int m0 = mgrp*32 + lk*4 + j, m1 = m0 + 16;
            ghs[kh][m0][lr]    = acc00[j];
            ghs[kh][m0][16+lr] = acc01[j];
            ghs[kh][m0][32+lr] = acc02[j];
            ghs[kh][m1][lr]    = acc10[j];
            ghs[kh][m1][16+lr] = acc11[j];
            ghs[kh][m1][32+lr] = acc12[j];
        }
        __syncthreads();
        // ---- gate fusion ----
        {
            int rid = idx8[gb*NS + i];
            float2 h2p = *(const float2*)(xf + ((size_t)gb*NS + rid)*NH + hg);
            float o0, o1;
            #pragma unroll
            for (int u=0; u<2; u++){
                int hl = hp*2 + u;
                float g1r = ghs[0][gb][hl]       + ghs[1][gb][hl]       + bhs[hl];
                float g1z = ghs[0][gb][16+hl]    + ghs[1][gb][16+hl]    + bhs[16+hl];
                float g1n = ghs[0][gb][32+hl]    + ghs[1][gb][32+hl]    + bhs[32+hl];
                float g2r = ghs[0][64+gb][hl]    + ghs[1][64+gb][hl]    + bhs[hl];
                float g2z = ghs[0][64+gb][16+hl] + ghs[1][64+gb][16+hl] + bhs[16+hl];
                float g2n = ghs[0][64+gb][32+hl] + ghs[1][64+gb][32+hl] + bhs[32+hl];
                float ir  = u ? cg0.y : cg0.x;
                float iz  = u ? cg1.y : cg1.x;
                float inn = u ? cg2.y : cg2.x;
                float hh1 = u ? h1prev.y : h1prev.x;
                float hh2 = u ? h2p.y : h2p.x;
                float r1v = sigmf(ir + g1r), z1 = sigmf(iz + g1z);
                float n1 = tanhf(inn + r1v*g1n);
                float hid1 = (1.f-z1)*n1 + z1*hh1;
                float r2v = sigmf(ir + g2r), z2 = sigmf(iz + g2z);
                float n2 = tanhf(inn + r2v*g2n);
                float hid2 = (1.f-z2)*n2 + z2*hh2;
                float v = cA.x*hid1 + cA.y*hid2;
                if (u) o1 = v; else o0 = v;
            }
            *(float2*)(xf + ((size_t)gb*NS + i)*NH + hg) = make_float2(o0, o1);
            unsigned pk = (unsigned)f2bf(o0) | ((unsigned)f2bf(o1) << 16);
            unsigned short* xaddr = xb + ((size_t)gb*NS + i)*NH + hg;
            asm volatile("global_store_dword %0, %1, off sc0" :: "v"(xaddr), "v"(pk) : "memory");
            h1prev = make_float2(o0, o1);
        }
        asm volatile("s_waitcnt vmcnt(0)" ::: "memory");
        __syncthreads();
        // ---- group barrier: AGENT atomics (LLC-executed add, coherent poll) ----
        if (i < NS-1){
            if (tid == 0){
                __hip_atomic_fetch_add(barp, 1, __ATOMIC_RELAXED, __HIP_MEMORY_SCOPE_AGENT);
                int target = GSZ * i;
                int spins = 0;
                while (__hip_atomic_load(barp, __ATOMIC_RELAXED, __HIP_MEMORY_SCOPE_AGENT) < target
                       && spins < (1<<17)){
                    spins++;
                    __builtin_amdgcn_s_sleep(2);
                }
            }
            __syncthreads();
        }
    }
}

// out_time: wave per row (reads f32 state)
__global__ void k_time(const float* __restrict__ xf, const float* __restrict__ W_time,
                       const float* __restrict__ b_time, float* __restrict__ out){
    int gw = (int)((blockIdx.x*(size_t)blockDim.x + threadIdx.x) >> 6);
    int lane = threadIdx.x & 63;
    if (gw >= NB*NS) return;
    const float* x = xf + (size_t)gw*NH;
    float s = 0.f;
    for (int k=lane;k<NH;k+=64) s += x[k]*W_time[k];
    for (int off=32; off; off>>=1) s += __shfl_down(s, off);
    if (lane == 0) out[gw] = s + b_time[0];
}

extern "C" void kernel_launch(void* const* d_in, const int* in_sizes, int n_in,
                              void* d_out, int out_size, void* d_ws, size_t ws_size,
                              hipStream_t stream){
    const float* src    = (const float*)d_in[0];
    const int*   lens   = (const int*)d_in[1];
    const int*   seq    = (const int*)d_in[2];
    const float* X      = (const float*)d_in[3];
    const float* A      = (const float*)d_in[4];
    const float* W_attn = (const float*)d_in[5];
    const float* a_attn = (const float*)d_in[6];
    const float* W_ih   = (const float*)d_in[7];
    const float* W_hh   = (const float*)d_in[8];
    const float* b_ih   = (const float*)d_in[9];
    const float* b_hh   = (const float*)d_in[10];
    const float* h0     = (const float*)d_in[11];
    const float* W_poi  = (const float*)d_in[12];
    const float* b_poi  = (const float*)d_in[13];
    const float* W_time = (const float*)d_in[14];
    const float* b_time = (const float*)d_in[15];
    const float* W_cat  = (const float*)d_in[16];
    const float* b_cat  = (const float*)d_in[17];

    // ws layout (~36 MB)
    char* ws = (char*)d_ws;
    float*          xf      = (float*)(ws + 0);                 // 16777216
    unsigned short* xb      = (unsigned short*)(ws + 16777216); // 8388608
    unsigned short* Whh_bf  = (unsigned short*)(ws + 25165824); // 1572864
    unsigned short* Wpoi_bf = (unsigned short*)(ws + 26738688); // 8388608
    unsigned short* Wcat_bf = (unsigned short*)(ws + 35127296); // 409600
    double*         wh1     = (double*)(ws + 35536896);         // 65536
    double*         wh2     = (double*)(ws + 35602432);         // 65536
    double*         c1d     = (double*)(ws + 35667968);         // 1024
    double*         c2d     = (double*)(ws + 35668992);         // 1024
    float*          alpha   = (float*)(ws + 35670016);          // 65536
    int*            idx     = (int*)(ws + 35735552);            // 32768
    float*          gh0     = (float*)(ws + 35768320);          // 6144
    int*            ctrl    = (int*)(ws + 35774464);            // 1280 (cnt[8], arrived, bar[8*32])

    // scratch inside the out_poi region of d_out (dead before out_poi GEMM runs)
    char* ob = (char*)d_out;
    unsigned short* src_bf = (unsigned short*)(ob + 0);         // 8388608
    unsigned short* Wih_bf = (unsigned short*)(ob + 9437184);   // 1572864
    float*          gi     = (float*)(ob + 16777216);           // 50331648

    float* out_poi  = (float*)d_out;                        // 8192 x 8192
    float* out_time = (float*)d_out + (size_t)8192*8192;    // 8192
    float* out_cat  = out_time + 8192;                      // 8192 x 400

    // conversions + control init
    k_zero<<<1, 512, 0, stream>>>(ctrl);
    k_cvt<<<4096, 256, 0, stream>>>(src, src_bf, NB*NS*NE);
    k_cvt<<<768, 256, 0, stream>>>(W_ih, Wih_bf, H3*NE);
    k_cvt<<<768, 256, 0, stream>>>(W_hh, Whh_bf, H3*NH);
    k_cvt<<<4096, 256, 0, stream>>>(W_poi, Wpoi_bf, NPOI_*NH);
    k_cvt<<<200, 256, 0, stream>>>(W_cat, Wcat_bf, NCAT_*NH);

    // attention path (f64, exact argmax)
    k_prep_c<<<1, 128, 0, stream>>>(W_attn, a_attn, c1d, c2d);
    k_wh<<<32, 256, 0, stream>>>(X, c1d, c2d, wh1, wh2);
    k_gh0<<<6, 256, 0, stream>>>(h0, W_hh, b_hh, gh0);
    k_attn<<<2048, 256, 0, stream>>>(seq, lens, A, wh1, wh2, alpha, idx);

    // gi = src @ W_ih^T + b_ih  (8192 x 1536, K=512)
    k_gemm_bf16<<<dim3(12, 64), 256, 0, stream>>>(src_bf, Wih_bf, b_ih, gi, NB*NS, H3, NE, H3);

    // scan
    k_step0<<<128, 256, 0, stream>>>(gi, gh0, h0, xf, xb);
    k_scan<<<NWG_LAUNCH, 512, 0, stream>>>(gi, Whh_bf, b_hh, alpha, idx, xf, xb, ctrl);

    // output projections
    k_gemm_bf16<<<dim3(64, 64), 256, 0, stream>>>(xb, Wpoi_bf, b_poi, out_poi, NB*NS, NPOI_, NH, NPOI_);
    k_gemm_bf16<<<dim3(4, 64), 256, 0, stream>>>(xb, Wcat_bf, b_cat, out_cat, NB*NS, NCAT_, NH, NCAT_);
    k_time<<<2048, 256, 0, stream>>>(xf, W_time, b_time, out_time);
}

// Round 9
// 1114.635 us; speedup vs baseline: 1.8179x; 1.0117x over previous
//
#include <hip/hip_runtime.h>
#include <math.h>

typedef __attribute__((ext_vector_type(8))) short short8;
typedef __attribute__((ext_vector_type(4))) float f32x4;

#define NB 64
#define NS 128
#define NE 512
#define NH 512
#define NPOI_ 8192
#define NCAT_ 400
#define NF_ 128
#define H3 1536
#define NEGV -1000000000.0
#define GSZ 32
#define NWG_LAUNCH 256

__device__ inline float sigmf(float x){ return 1.0f/(1.0f + expf(-x)); }
__device__ inline unsigned short f2bf(float f){
    unsigned u = __float_as_uint(f);
    unsigned r = (u + 0x7fffu + ((u>>16)&1u)) >> 16;
    return (unsigned short)r;
}

// 16B load hinted to stop at L2 (correct regardless of L1 behavior: rows are write-once)
#define LD16C(d, p, o) asm volatile("global_load_dwordx4 %0, %1, off offset:" o " sc0" : "=&v"(d) : "v"(p))

// ---------- f32 -> bf16 conversion (n multiple of 4) ----------
__global__ void k_cvt(const float* __restrict__ in, unsigned short* __restrict__ out, int n){
    int t = blockIdx.x*blockDim.x + threadIdx.x;
    int i = t*4;
    if (i < n){
        float4 v = *(const float4*)(in + i);
        ushort4 o;
        o.x = f2bf(v.x); o.y = f2bf(v.y); o.z = f2bf(v.z); o.w = f2bf(v.w);
        *(ushort4*)(out + i) = o;
    }
}

// clear control region; winner slot = -1
__global__ void k_zero(int* p){
    for (int t = threadIdx.x; t < 256 + 8*GSZ*32; t += blockDim.x) p[t] = 0;
    __syncthreads();
    if (threadIdx.x == 0) p[9] = -1;
}

// ---------- phase 1: attention precompute (f64 for argmax stability) ----------
__global__ void k_prep_c(const float* __restrict__ W_attn, const float* __restrict__ a_attn,
                         double* __restrict__ c1d, double* __restrict__ c2d){
    int f = blockIdx.x*blockDim.x + threadIdx.x;
    if (f < NF_){
        double s1=0.0, s2=0.0;
        for (int k=0;k<NF_;k++){
            double w = (double)W_attn[f*NF_+k];
            s1 += w*(double)a_attn[k];
            s2 += w*(double)a_attn[NF_+k];
        }
        c1d[f]=s1; c2d[f]=s2;
    }
}

__global__ void k_wh(const float* __restrict__ X, const double* __restrict__ c1d,
                     const double* __restrict__ c2d, double* __restrict__ wh1, double* __restrict__ wh2){
    int p = blockIdx.x*blockDim.x + threadIdx.x;
    if (p < NPOI_){
        const float* x = X + (size_t)p*NF_;
        double s1=0.0,s2=0.0;
        for (int k=0;k<NF_;k++){ double xv=(double)x[k]; s1+=xv*c1d[k]; s2+=xv*c2d[k]; }
        wh1[p]=s1; wh2[p]=s2;
    }
}

__global__ void k_gh0(const float* __restrict__ h0, const float* __restrict__ W_hh,
                      const float* __restrict__ b_hh, float* __restrict__ gh0){
    int c = blockIdx.x*blockDim.x + threadIdx.x;
    if (c < H3){
        const float* w = W_hh + (size_t)c*NH;
        float s=0.f;
        for (int k=0;k<NH;k++) s += h0[k]*w[k];
        gh0[c] = s + b_hh[c];
    }
}

__device__ inline double shfl_down_d(double x, int off){
    long long v = __double_as_longlong(x);
    int lo = (int)(v & 0xffffffffLL), hi = (int)(((unsigned long long)v)>>32);
    lo = __shfl_down(lo, off); hi = __shfl_down(hi, off);
    return __longlong_as_double(((long long)hi<<32) | (unsigned long long)(unsigned int)lo);
}

__global__ void k_attn(const int* __restrict__ seq, const int* __restrict__ lens,
                       const float* __restrict__ A, const double* __restrict__ wh1,
                       const double* __restrict__ wh2, float* __restrict__ alpha,
                       int* __restrict__ idxout){
    int gw = (int)((blockIdx.x*(size_t)blockDim.x + threadIdx.x) >> 6);
    int lane = threadIdx.x & 63;
    if (gw >= NB*NS) return;
    int b = gw >> 7, j = gw & 127;
    int len = lens[b];
    int q = seq[b*NS + j];
    double wq = wh2[q];
    bool jvalid = (j < len);
    double mval = -1.0e300; int mk = 0;
    for (int k0=0;k0<NS;k0+=64){
        int k = k0 + lane;
        double val = NEGV;
        if (k < j && jvalid){
            int p = seq[b*NS + k];
            double e = wh1[p] + wq;
            e = (e > 0.0) ? e : 0.2*e;
            val = e * ((double)A[(size_t)p*NPOI_ + q] + 1.0);
        }
        if (val > mval){ mval = val; mk = k; }
    }
    for (int off=32; off; off>>=1){
        double ov = shfl_down_d(mval, off);
        int ok = __shfl_down(mk, off);
        if (ov > mval || (ov == mval && ok < mk)){ mval = ov; mk = ok; }
    }
    if (lane == 0){
        double v0 = mval;
        double v1;
        if (j == 0) v1 = 0.0;
        else if (!jvalid) v1 = NEGV;
        else {
            int p = seq[b*NS + j - 1];
            double e = wh1[p] + wq;
            e = (e > 0.0) ? e : 0.2*e;
            v1 = e * ((double)A[(size_t)p*NPOI_ + q] + 1.0);
        }
        double m = fmax(v0, v1);
        double e0 = exp(v0 - m), e1 = exp(v1 - m);
        double den = e0 + e1;
        alpha[(size_t)(b*NS+j)*2 + 0] = (float)(e0/den);
        alpha[(size_t)(b*NS+j)*2 + 1] = (float)(e1/den);
        idxout[b*NS + j] = mk;
    }
}

// ---------- bf16 MFMA NT GEMM: C[r,c] = sum_k A[r,k]*B[c,k] + bias[c] ----------
#define LDT 88
__global__ __launch_bounds__(256) void k_gemm_bf16(const unsigned short* __restrict__ A,
        const unsigned short* __restrict__ B, const float* __restrict__ bias,
        float* __restrict__ C, int M, int N, int K, int ldc){
    __shared__ unsigned short As[128][LDT];
    __shared__ unsigned short Bs[128][LDT];
    int row0 = blockIdx.y*128, col0 = blockIdx.x*128;
    int tid = threadIdx.x;
    int lane = tid & 63, w = tid >> 6;
    int wr = w >> 1, wc = w & 1;
    int lr = lane & 15, lk = lane >> 4;
    f32x4 acc[4][4] = {};
    for (int k0 = 0; k0 < K; k0 += 64){
        #pragma unroll
        for (int q = 0; q < 4; q++){
            int c = tid + 256*q;
            int r = c >> 3, ko = (c & 7)*8;
            *(short8*)&As[r][ko] = *(const short8*)(A + (size_t)(row0+r)*K + k0 + ko);
            int gc = col0 + r;
            short8 bv = {};
            if (gc < N) bv = *(const short8*)(B + (size_t)gc*K + k0 + ko);
            *(short8*)&Bs[r][ko] = bv;
        }
        __syncthreads();
        #pragma unroll
        for (int ks = 0; ks < 2; ks++){
            int kf = ks*32 + lk*8;
            short8 af[4], bf_[4];
            #pragma unroll
            for (int m=0;m<4;m++) af[m] = *(const short8*)&As[wr*64 + m*16 + lr][kf];
            #pragma unroll
            for (int n=0;n<4;n++) bf_[n] = *(const short8*)&Bs[wc*64 + n*16 + lr][kf];
            #pragma unroll
            for (int m=0;m<4;m++)
                #pragma unroll
                for (int n=0;n<4;n++)
                    acc[m][n] = __builtin_amdgcn_mfma_f32_16x16x32_bf16(af[m], bf_[n], acc[m][n], 0,0,0);
        }
        __syncthreads();
    }
    #pragma unroll
    for (int m=0;m<4;m++){
        #pragma unroll
        for (int n=0;n<4;n++){
            int col = col0 + wc*64 + n*16 + lr;
            if (col < N){
                float bb = bias[col];
                #pragma unroll
                for (int j=0;j<4;j++){
                    int row = row0 + wr*64 + m*16 + lk*4 + j;
                    C[(size_t)row*ldc + col] = acc[m][n][j] + bb;
                }
            }
        }
    }
}

// ---------- scan: i=0 ----------
__global__ void k_step0(const float* __restrict__ gi, const float* __restrict__ gh0,
                        const float* __restrict__ h0, float* __restrict__ xf,
                        unsigned short* __restrict__ xb){
    int t = blockIdx.x*blockDim.x + threadIdx.x;
    if (t >= NB*NH) return;
    int b = t >> 9, h = t & 511;
    const float* g = gi + (size_t)b*NS*H3;
    float r = sigmf(g[h] + gh0[h]);
    float z = sigmf(g[512+h] + gh0[512+h]);
    float n = tanhf(g[1024+h] + r*gh0[1024+h]);
    float v = (1.f-z)*n + z*h0[h];
    size_t o = (size_t)b*NS*NH + h;
    xf[o] = v;
    xb[o] = f2bf(v);
}

// ---------- persistent scan v6: ONE group on ONE XCD, atomic-RMW flag barrier ----------
// r8 lesson: never poll plain loads for cross-CU values (stale L1/clean-L2 copies are
// never invalidated). Every flag access here is an atomic RMW (exchange/add/add-0):
// RMWs execute at a cache that owns the line (L2+), one uniform path => coherent.
// Single winner XCD => producer L2 == consumer L2 for the data path too.
__global__ __launch_bounds__(512, 2) void k_scan(const float* __restrict__ gi,
        const unsigned short* __restrict__ Whh, const float* __restrict__ bhh,
        const float* __restrict__ alpha, const int* __restrict__ idx,
        float* __restrict__ xf, unsigned short* __restrict__ xb, int* __restrict__ ctrl){
    __shared__ float ghs[2][128][50];
    __shared__ unsigned char idx8[NB*NS];
    __shared__ float bhs[48];
    __shared__ int s_go, s_rank;
    const int tid = threadIdx.x;

    // ---- election: winner-take-all XCD (AGENT atomics, one-time) ----
    if (tid == 0){
        int x;
        asm volatile("s_getreg_b32 %0, hwreg(HW_REG_XCC_ID)" : "=s"(x));
        x &= 7;
        int r = __hip_atomic_fetch_add(&ctrl[x], 1, __ATOMIC_RELAXED, __HIP_MEMORY_SCOPE_AGENT);
        int go = 0;
        if (r < GSZ){
            if (r == GSZ-1){   // completer: claim winner slot
                int exp = -1;
                __hip_atomic_compare_exchange_strong(&ctrl[9], &exp, x,
                    __ATOMIC_RELAXED, __ATOMIC_RELAXED, __HIP_MEMORY_SCOPE_AGENT);
            }
            int spins = 0, wn;
            while ((wn = __hip_atomic_load(&ctrl[9], __ATOMIC_RELAXED, __HIP_MEMORY_SCOPE_AGENT)) == -1
                   && spins < (1<<20)){
                spins++;
                __builtin_amdgcn_s_sleep(1);
            }
            go = (wn == x);
        }
        s_go = go; s_rank = r;
    }
    __syncthreads();
    if (!s_go) return;
    const int g = s_rank;                      // h-slice [g*16, g*16+16)
    int* const flagbase = ctrl + 256;
    int* const myflag   = flagbase + g*32;     // 128B-separated flag lines

    // ---- flag init: exchange (pure write, stale-basis-immune) + AGENT init barrier ----
    if (tid == 0){
        __hip_atomic_exchange(myflag, 0, __ATOMIC_RELAXED, __HIP_MEMORY_SCOPE_AGENT);
        __hip_atomic_fetch_add(&ctrl[10], 1, __ATOMIC_RELAXED, __HIP_MEMORY_SCOPE_AGENT);
        int spins = 0;
        while (__hip_atomic_load(&ctrl[10], __ATOMIC_RELAXED, __HIP_MEMORY_SCOPE_AGENT) < GSZ
               && spins < (1<<20)){
            spins++;
            __builtin_amdgcn_s_sleep(1);
        }
    }
    __syncthreads();

    // ---- one-time staging ----
    const int lane = tid & 63, w = tid >> 6;
    const int kh = w & 1, mgrp = w >> 1;
    const int lr = lane & 15, lk = lane >> 4;

    short8 bw0[8], bw1[8], bw2[8];
    {
        const unsigned short* wb = Whh + ((size_t)(g*16 + lr))*NH + kh*256 + lk*8;
        #pragma unroll
        for (int ks=0; ks<8; ks++){
            bw0[ks] = *(const short8*)(wb + 0*262144 + ks*32);
            bw1[ks] = *(const short8*)(wb + 1*262144 + ks*32);
            bw2[ks] = *(const short8*)(wb + 2*262144 + ks*32);
        }
    }
    if (tid < 48) bhs[tid] = bhh[(tid>>4)*512 + g*16 + (tid&15)];
    for (int c = tid; c < NB*NS; c += 512) idx8[c] = (unsigned char)idx[c];

    const int gb = tid >> 3, hp = tid & 7;     // gate phase: batch gb, h-pair hp
    const int hg = g*16 + hp*2;

    const int r0 = mgrp*32 + lr, r1 = r0 + 16;
    const int ab0 = r0 & 63, ab1 = r1 & 63;
    const int v0_ = r0 >> 6, v1_ = r1 >> 6;

    int* const pollp = flagbase + (lane & 31)*32;   // wave0's per-lane poll addr

    float2 h1prev = *(const float2*)(xf + ((size_t)gb*NS)*NH + hg);
    float2 nx0 = *(const float2*)(gi + ((size_t)gb*NS + 1)*H3 + hg);
    float2 nx1 = *(const float2*)(gi + ((size_t)gb*NS + 1)*H3 + 512 + hg);
    float2 nx2 = *(const float2*)(gi + ((size_t)gb*NS + 1)*H3 + 1024 + hg);
    float2 nxA = *(const float2*)(alpha + ((size_t)gb*NS + 1)*2);
    __syncthreads();

    for (int i = 1; i < NS; i++){
        float2 cg0 = nx0, cg1 = nx1, cg2 = nx2, cA = nxA;
        // ---- A-loads ----
        int s0 = v0_ ? (int)idx8[ab0*NS + i] : (i-1);
        int s1 = v1_ ? (int)idx8[ab1*NS + i] : (i-1);
        const unsigned short* ap0 = xb + ((size_t)ab0*NS + s0)*NH + kh*256 + lk*8;
        const unsigned short* ap1 = xb + ((size_t)ab1*NS + s1)*NH + kh*256 + lk*8;
        short8 a0[8], a1[8];
        LD16C(a0[0], ap0, "0");   LD16C(a0[1], ap0, "64");  LD16C(a0[2], ap0, "128"); LD16C(a0[3], ap0, "192");
        LD16C(a0[4], ap0, "256"); LD16C(a0[5], ap0, "320"); LD16C(a0[6], ap0, "384"); LD16C(a0[7], ap0, "448");
        LD16C(a1[0], ap1, "0");   LD16C(a1[1], ap1, "64");  LD16C(a1[2], ap1, "128"); LD16C(a1[3], ap1, "192");
        LD16C(a1[4], ap1, "256"); LD16C(a1[5], ap1, "320"); LD16C(a1[6], ap1, "384"); LD16C(a1[7], ap1, "448");
        asm volatile("s_waitcnt vmcnt(0)" ::: "memory");
        __builtin_amdgcn_sched_barrier(0);
        f32x4 acc00 = {}, acc01 = {}, acc02 = {}, acc10 = {}, acc11 = {}, acc12 = {};
        #pragma unroll
        for (int ks=0; ks<8; ks++){
            acc00 = __builtin_amdgcn_mfma_f32_16x16x32_bf16(a0[ks], bw0[ks], acc00, 0,0,0);
            acc01 = __builtin_amdgcn_mfma_f32_16x16x32_bf16(a0[ks], bw1[ks], acc01, 0,0,0);
            acc02 = __builtin_amdgcn_mfma_f32_16x16x32_bf16(a0[ks], bw2[ks], acc02, 0,0,0);
            acc10 = __builtin_amdgcn_mfma_f32_16x16x32_bf16(a1[ks], bw0[ks], acc10, 0,0,0);
            acc11 = __builtin_amdgcn_mfma_f32_16x16x32_bf16(a1[ks], bw1[ks], acc11, 0,0,0);
            acc12 = __builtin_amdgcn_mfma_f32_16x16x32_bf16(a1[ks], bw2[ks], acc12, 0,0,0);
        }
        // prefetch next step's static operands (off critical path)
        {
            int ip = (i+1 < NS) ? (i+1) : (NS-1);
            nx0 = *(const float2*)(gi + ((size_t)gb*NS + ip)*H3 + hg);
            nx1 = *(const float2*)(gi + ((size_t)gb*NS + ip)*H3 + 512 + hg);
            nx2 = *(const float2*)(gi + ((size_t)gb*NS + ip)*H3 + 1024 + hg);
            nxA = *(const float2*)(alpha + ((size_t)gb*NS + ip)*2);
        }
        #pragma unroll
        for (int j=0;j<4;j++){
            int m0 = mgrp*32 + lk*4 + j, m1 = m0 + 16;
            ghs[kh][m0][lr]    = acc00[j];
            ghs[kh][m0][16+lr] = acc01[j];
            ghs[kh][m0][32+lr] = acc02[j];
            ghs[kh][m1][lr]    = acc10[j];
            ghs[kh][m1][16+lr] = acc11[j];
            ghs[kh][m1][32+lr] = acc12[j];
        }
        __syncthreads();
        // ---- gate fusion ----
        {
            int rid = idx8[gb*NS + i];
            float2 h2p = *(const float2*)(xf + ((size_t)gb*NS + rid)*NH + hg);
            float o0, o1;
            #pragma unroll
            for (int u=0; u<2; u++){
                int hl = hp*2 + u;
                float g1r = ghs[0][gb][hl]       + ghs[1][gb][hl]       + bhs[hl];
                float g1z = ghs[0][gb][16+hl]    + ghs[1][gb][16+hl]    + bhs[16+hl];
                float g1n = ghs[0][gb][32+hl]    + ghs[1][gb][32+hl]    + bhs[32+hl];
                float g2r = ghs[0][64+gb][hl]    + ghs[1][64+gb][hl]    + bhs[hl];
                float g2z = ghs[0][64+gb][16+hl] + ghs[1][64+gb][16+hl] + bhs[16+hl];
                float g2n = ghs[0][64+gb][32+hl] + ghs[1][64+gb][32+hl] + bhs[32+hl];
                float ir  = u ? cg0.y : cg0.x;
                float iz  = u ? cg1.y : cg1.x;
                float inn = u ? cg2.y : cg2.x;
                float hh1 = u ? h1prev.y : h1prev.x;
                float hh2 = u ? h2p.y : h2p.x;
                float r1v = sigmf(ir + g1r), z1 = sigmf(iz + g1z);
                float n1 = tanhf(inn + r1v*g1n);
                float hid1 = (1.f-z1)*n1 + z1*hh1;
                float r2v = sigmf(ir + g2r), z2 = sigmf(iz + g2z);
                float n2 = tanhf(inn + r2v*g2n);
                float hid2 = (1.f-z2)*n2 + z2*hh2;
                float v = cA.x*hid1 + cA.y*hid2;
                if (u) o1 = v; else o0 = v;
            }
            *(float2*)(xf + ((size_t)gb*NS + i)*NH + hg) = make_float2(o0, o1);
            unsigned pk = (unsigned)f2bf(o0) | ((unsigned)f2bf(o1) << 16);
            unsigned short* xaddr = xb + ((size_t)gb*NS + i)*NH + hg;
            asm volatile("global_store_dword %0, %1, off sc0" :: "v"(xaddr), "v"(pk) : "memory");
            h1prev = make_float2(o0, o1);
        }
        asm volatile("s_waitcnt vmcnt(0)" ::: "memory");   // data committed to L2
        __syncthreads();                                    // all waves' data in L2
        // ---- flag barrier: atomic-RMW signal + atomic-RMW poll ----
        if (i < NS-1){
            if (tid == 0)
                __hip_atomic_fetch_add(myflag, 1, __ATOMIC_RELAXED, __HIP_MEMORY_SCOPE_AGENT);
            if (w == 0){
                int spins = 0;
                while (1){
                    int v = __hip_atomic_fetch_add(pollp, 0, __ATOMIC_RELAXED, __HIP_MEMORY_SCOPE_AGENT);
                    if (__all(v >= i)) break;
                    if (++spins > (1<<20)) break;
                    __builtin_amdgcn_s_sleep(1);
                }
            }
            __syncthreads();
        }
    }
}

// out_time: wave per row (reads f32 state)
__global__ void k_time(const float* __restrict__ xf, const float* __restrict__ W_time,
                       const float* __restrict__ b_time, float* __restrict__ out){
    int gw = (int)((blockIdx.x*(size_t)blockDim.x + threadIdx.x) >> 6);
    int lane = threadIdx.x & 63;
    if (gw >= NB*NS) return;
    const float* x = xf + (size_t)gw*NH;
    float s = 0.f;
    for (int k=lane;k<NH;k+=64) s += x[k]*W_time[k];
    for (int off=32; off; off>>=1) s += __shfl_down(s, off);
    if (lane == 0) out[gw] = s + b_time[0];
}

extern "C" void kernel_launch(void* const* d_in, const int* in_sizes, int n_in,
                              void* d_out, int out_size, void* d_ws, size_t ws_size,
                              hipStream_t stream){
    const float* src    = (const float*)d_in[0];
    const int*   lens   = (const int*)d_in[1];
    const int*   seq    = (const int*)d_in[2];
    const float* X      = (const float*)d_in[3];
    const float* A      = (const float*)d_in[4];
    const float* W_attn = (const float*)d_in[5];
    const float* a_attn = (const float*)d_in[6];
    const float* W_ih   = (const float*)d_in[7];
    const float* W_hh   = (const float*)d_in[8];
    const float* b_ih   = (const float*)d_in[9];
    const float* b_hh   = (const float*)d_in[10];
    const float* h0     = (const float*)d_in[11];
    const float* W_poi  = (const float*)d_in[12];
    const float* b_poi  = (const float*)d_in[13];
    const float* W_time = (const float*)d_in[14];
    const float* b_time = (const float*)d_in[15];
    const float* W_cat  = (const float*)d_in[16];
    const float* b_cat  = (const float*)d_in[17];

    // ws layout (~36 MB)
    char* ws = (char*)d_ws;
    float*          xf      = (float*)(ws + 0);                 // 16777216
    unsigned short* xb      = (unsigned short*)(ws + 16777216); // 8388608
    unsigned short* Whh_bf  = (unsigned short*)(ws + 25165824); // 1572864
    unsigned short* Wpoi_bf = (unsigned short*)(ws + 26738688); // 8388608
    unsigned short* Wcat_bf = (unsigned short*)(ws + 35127296); // 409600
    double*         wh1     = (double*)(ws + 35536896);         // 65536
    double*         wh2     = (double*)(ws + 35602432);         // 65536
    double*         c1d     = (double*)(ws + 35667968);         // 1024
    double*         c2d     = (double*)(ws + 35668992);         // 1024
    float*          alpha   = (float*)(ws + 35670016);          // 65536
    int*            idx     = (int*)(ws + 35735552);            // 32768
    float*          gh0     = (float*)(ws + 35768320);          // 6144
    int*            ctrl    = (int*)(ws + 35774464);            // cnt[8], winner[9], init[10], flags @+256

    // scratch inside the out_poi region of d_out (dead before out_poi GEMM runs)
    char* ob = (char*)d_out;
    unsigned short* src_bf = (unsigned short*)(ob + 0);         // 8388608
    unsigned short* Wih_bf = (unsigned short*)(ob + 9437184);   // 1572864
    float*          gi     = (float*)(ob + 16777216);           // 50331648

    float* out_poi  = (float*)d_out;                        // 8192 x 8192
    float* out_time = (float*)d_out + (size_t)8192*8192;    // 8192
    float* out_cat  = out_time + 8192;                      // 8192 x 400

    // conversions + control init
    k_zero<<<1, 512, 0, stream>>>(ctrl);
    k_cvt<<<4096, 256, 0, stream>>>(src, src_bf, NB*NS*NE);
    k_cvt<<<768, 256, 0, stream>>>(W_ih, Wih_bf, H3*NE);
    k_cvt<<<768, 256, 0, stream>>>(W_hh, Whh_bf, H3*NH);
    k_cvt<<<4096, 256, 0, stream>>>(W_poi, Wpoi_bf, NPOI_*NH);
    k_cvt<<<200, 256, 0, stream>>>(W_cat, Wcat_bf, NCAT_*NH);

    // attention path (f64, exact argmax)
    k_prep_c<<<1, 128, 0, stream>>>(W_attn, a_attn, c1d, c2d);
    k_wh<<<32, 256, 0, stream>>>(X, c1d, c2d, wh1, wh2);
    k_gh0<<<6, 256, 0, stream>>>(h0, W_hh, b_hh, gh0);
    k_attn<<<2048, 256, 0, stream>>>(seq, lens, A, wh1, wh2, alpha, idx);

    // gi = src @ W_ih^T + b_ih  (8192 x 1536, K=512)
    k_gemm_bf16<<<dim3(12, 64), 256, 0, stream>>>(src_bf, Wih_bf, b_ih, gi, NB*NS, H3, NE, H3);

    // scan
    k_step0<<<128, 256, 0, stream>>>(gi, gh0, h0, xf, xb);
    k_scan<<<NWG_LAUNCH, 512, 0, stream>>>(gi, Whh_bf, b_hh, alpha, idx, xf, xb, ctrl);

    // output projections
    k_gemm_bf16<<<dim3(64, 64), 256, 0, stream>>>(xb, Wpoi_bf, b_poi, out_poi, NB*NS, NPOI_, NH, NPOI_);
    k_gemm_bf16<<<dim3(4, 64), 256, 0, stream>>>(xb, Wcat_bf, b_cat, out_cat, NB*NS, NCAT_, NH, NCAT_);
    k_time<<<2048, 256, 0, stream>>>(xf, W_time, b_time, out_time);
}

// Round 10
// 1102.023 us; speedup vs baseline: 1.8387x; 1.0114x over previous
//
#include <hip/hip_runtime.h>
#include <math.h>

typedef __attribute__((ext_vector_type(8))) short short8;
typedef __attribute__((ext_vector_type(4))) float f32x4;

#define NB 64
#define NS 128
#define NE 512
#define NH 512
#define NPOI_ 8192
#define NCAT_ 400
#define NF_ 128
#define H3 1536
#define NEGV -1000000000.0
#define GSZ 32
#define NWG_LAUNCH 256

__device__ inline float sigmf(float x){ return 1.0f/(1.0f + expf(-x)); }
__device__ inline unsigned short f2bf(float f){
    unsigned u = __float_as_uint(f);
    unsigned r = (u + 0x7fffu + ((u>>16)&1u)) >> 16;
    return (unsigned short)r;
}

// 16B load hinted to stop at L2
#define LD16C(d, p, o) asm volatile("global_load_dwordx4 %0, %1, off offset:" o " sc0" : "=&v"(d) : "v"(p))

// ---------- f32 -> bf16 conversion ----------
__global__ void k_cvt(const float* __restrict__ in, unsigned short* __restrict__ out, int n){
    int t = blockIdx.x*blockDim.x + threadIdx.x;
    int i = t*4;
    if (i < n){
        float4 v = *(const float4*)(in + i);
        ushort4 o;
        o.x = f2bf(v.x); o.y = f2bf(v.y); o.z = f2bf(v.z); o.w = f2bf(v.w);
        *(ushort4*)(out + i) = o;
    }
}

__global__ void k_zero(int* p){
    for (int t = threadIdx.x; t < 256 + 8*GSZ*32; t += blockDim.x) p[t] = 0;
    __syncthreads();
    if (threadIdx.x == 0) p[9] = -1;
}

// ---------- attention precompute (f64 for argmax stability) ----------
__global__ void k_prep_c(const float* __restrict__ W_attn, const float* __restrict__ a_attn,
                         double* __restrict__ c1d, double* __restrict__ c2d){
    int f = blockIdx.x*blockDim.x + threadIdx.x;
    if (f < NF_){
        double s1=0.0, s2=0.0;
        for (int k=0;k<NF_;k++){
            double w = (double)W_attn[f*NF_+k];
            s1 += w*(double)a_attn[k];
            s2 += w*(double)a_attn[NF_+k];
        }
        c1d[f]=s1; c2d[f]=s2;
    }
}

__global__ void k_wh(const float* __restrict__ X, const double* __restrict__ c1d,
                     const double* __restrict__ c2d, double* __restrict__ wh1, double* __restrict__ wh2){
    int p = blockIdx.x*blockDim.x + threadIdx.x;
    if (p < NPOI_){
        const float* x = X + (size_t)p*NF_;
        double s1=0.0,s2=0.0;
        for (int k=0;k<NF_;k++){ double xv=(double)x[k]; s1+=xv*c1d[k]; s2+=xv*c2d[k]; }
        wh1[p]=s1; wh2[p]=s2;
    }
}

__global__ void k_gh0(const float* __restrict__ h0, const float* __restrict__ W_hh,
                      const float* __restrict__ b_hh, float* __restrict__ gh0){
    int c = blockIdx.x*blockDim.x + threadIdx.x;
    if (c < H3){
        const float* w = W_hh + (size_t)c*NH;
        float s=0.f;
        for (int k=0;k<NH;k++) s += h0[k]*w[k];
        gh0[c] = s + b_hh[c];
    }
}

__device__ inline double shfl_down_d(double x, int off){
    long long v = __double_as_longlong(x);
    int lo = (int)(v & 0xffffffffLL), hi = (int)(((unsigned long long)v)>>32);
    lo = __shfl_down(lo, off); hi = __shfl_down(hi, off);
    return __longlong_as_double(((long long)hi<<32) | (unsigned long long)(unsigned int)lo);
}

__global__ void k_attn(const int* __restrict__ seq, const int* __restrict__ lens,
                       const float* __restrict__ A, const double* __restrict__ wh1,
                       const double* __restrict__ wh2, float* __restrict__ alpha,
                       int* __restrict__ idxout){
    int gw = (int)((blockIdx.x*(size_t)blockDim.x + threadIdx.x) >> 6);
    int lane = threadIdx.x & 63;
    if (gw >= NB*NS) return;
    int b = gw >> 7, j = gw & 127;
    int len = lens[b];
    int q = seq[b*NS + j];
    double wq = wh2[q];
    bool jvalid = (j < len);
    double mval = -1.0e300; int mk = 0;
    for (int k0=0;k0<NS;k0+=64){
        int k = k0 + lane;
        double val = NEGV;
        if (k < j && jvalid){
            int p = seq[b*NS + k];
            double e = wh1[p] + wq;
            e = (e > 0.0) ? e : 0.2*e;
            val = e * ((double)A[(size_t)p*NPOI_ + q] + 1.0);
        }
        if (val > mval){ mval = val; mk = k; }
    }
    for (int off=32; off; off>>=1){
        double ov = shfl_down_d(mval, off);
        int ok = __shfl_down(mk, off);
        if (ov > mval || (ov == mval && ok < mk)){ mval = ov; mk = ok; }
    }
    if (lane == 0){
        double v0 = mval;
        double v1;
        if (j == 0) v1 = 0.0;
        else if (!jvalid) v1 = NEGV;
        else {
            int p = seq[b*NS + j - 1];
            double e = wh1[p] + wq;
            e = (e > 0.0) ? e : 0.2*e;
            v1 = e * ((double)A[(size_t)p*NPOI_ + q] + 1.0);
        }
        double m = fmax(v0, v1);
        double e0 = exp(v0 - m), e1 = exp(v1 - m);
        double den = e0 + e1;
        alpha[(size_t)(b*NS+j)*2 + 0] = (float)(e0/den);
        alpha[(size_t)(b*NS+j)*2 + 1] = (float)(e1/den);
        idxout[b*NS + j] = mk;
    }
}

// ---------- bf16 MFMA NT GEMM with XCD-aware block swizzle ----------
#define LDT 88
__global__ __launch_bounds__(256) void k_gemm_bf16(const unsigned short* __restrict__ A,
        const unsigned short* __restrict__ B, const float* __restrict__ bias,
        float* __restrict__ C, int M, int N, int K, int ldc){
    __shared__ unsigned short As[128][LDT];
    __shared__ unsigned short Bs[128][LDT];
    // XCD swizzle (grid size divisible by 8): contiguous logical chunk per XCD
    int nwg = gridDim.x*gridDim.y;
    int lin = blockIdx.y*gridDim.x + blockIdx.x;
    int l2 = (lin & 7)*(nwg >> 3) + (lin >> 3);
    int bm = l2 / gridDim.x, bn = l2 % gridDim.x;
    int row0 = bm*128, col0 = bn*128;
    int tid = threadIdx.x;
    int lane = tid & 63, w = tid >> 6;
    int wr = w >> 1, wc = w & 1;
    int lr = lane & 15, lk = lane >> 4;
    f32x4 acc[4][4] = {};
    for (int k0 = 0; k0 < K; k0 += 64){
        #pragma unroll
        for (int q = 0; q < 4; q++){
            int c = tid + 256*q;
            int r = c >> 3, ko = (c & 7)*8;
            *(short8*)&As[r][ko] = *(const short8*)(A + (size_t)(row0+r)*K + k0 + ko);
            int gc = col0 + r;
            short8 bv = {};
            if (gc < N) bv = *(const short8*)(B + (size_t)gc*K + k0 + ko);
            *(short8*)&Bs[r][ko] = bv;
        }
        __syncthreads();
        #pragma unroll
        for (int ks = 0; ks < 2; ks++){
            int kf = ks*32 + lk*8;
            short8 af[4], bf_[4];
            #pragma unroll
            for (int m=0;m<4;m++) af[m] = *(const short8*)&As[wr*64 + m*16 + lr][kf];
            #pragma unroll
            for (int n=0;n<4;n++) bf_[n] = *(const short8*)&Bs[wc*64 + n*16 + lr][kf];
            #pragma unroll
            for (int m=0;m<4;m++)
                #pragma unroll
                for (int n=0;n<4;n++)
                    acc[m][n] = __builtin_amdgcn_mfma_f32_16x16x32_bf16(af[m], bf_[n], acc[m][n], 0,0,0);
        }
        __syncthreads();
    }
    #pragma unroll
    for (int m=0;m<4;m++){
        #pragma unroll
        for (int n=0;n<4;n++){
            int col = col0 + wc*64 + n*16 + lr;
            if (col < N){
                float bb = bias[col];
                #pragma unroll
                for (int j=0;j<4;j++){
                    int row = row0 + wr*64 + m*16 + lk*4 + j;
                    C[(size_t)row*ldc + col] = acc[m][n][j] + bb;
                }
            }
        }
    }
}

// ---------- persistent scan v7: hot polls, busy-keepers, step0 folded, early A-loads ----------
__global__ __launch_bounds__(512, 2) void k_scan(const float* __restrict__ gi,
        const unsigned short* __restrict__ Whh, const float* __restrict__ bhh,
        const float* __restrict__ alpha, const int* __restrict__ idx,
        const float* __restrict__ gh0, const float* __restrict__ h0v,
        float* __restrict__ xf, unsigned short* __restrict__ xb, int* __restrict__ ctrl){
    __shared__ float ghs[2][128][50];
    __shared__ unsigned char idx8[NB*NS];
    __shared__ float bhs[48];
    __shared__ int s_go, s_rank;
    const int tid = threadIdx.x;

    // ---- election: winner-take-all XCD (one-time, AGENT atomics) ----
    if (tid == 0){
        int x;
        asm volatile("s_getreg_b32 %0, hwreg(HW_REG_XCC_ID)" : "=s"(x));
        x &= 7;
        int r = __hip_atomic_fetch_add(&ctrl[x], 1, __ATOMIC_RELAXED, __HIP_MEMORY_SCOPE_AGENT);
        int go = 0;
        if (r < GSZ){
            if (r == GSZ-1){
                int exp = -1;
                __hip_atomic_compare_exchange_strong(&ctrl[9], &exp, x,
                    __ATOMIC_RELAXED, __ATOMIC_RELAXED, __HIP_MEMORY_SCOPE_AGENT);
            }
            int spins = 0, wn;
            while ((wn = __hip_atomic_load(&ctrl[9], __ATOMIC_RELAXED, __HIP_MEMORY_SCOPE_AGENT)) == -1
                   && spins < (1<<17)){
                spins++;
                __builtin_amdgcn_s_sleep(1);
            }
            go = (wn == x);
        }
        s_go = go; s_rank = r;
    }
    __syncthreads();
    if (!s_go){
        // ---- busy-keeper: hold clocks up until scan completes ----
        int spins = 0;
        float ka = 1.0f;
        while (spins < (1<<17)){
            #pragma unroll
            for (int q=0;q<64;q++) ka = fmaf(ka, 0.9999999f, 1e-9f);
            spins++;
            if ((spins & 15) == 0){
                if (__hip_atomic_load(&ctrl[11], __ATOMIC_RELAXED, __HIP_MEMORY_SCOPE_AGENT) >= GSZ) break;
            }
        }
        asm volatile("" :: "v"(ka));
        return;
    }
    const int g = s_rank;                      // h-slice [g*16, g*16+16)
    int* const flagbase = ctrl + 256;
    int* const myflag   = flagbase + g*32;     // 128B-separated monotonic step counters

    // ---- one-time staging ----
    const int lane = tid & 63, w = tid >> 6;
    const int kh = w & 1, mgrp = w >> 1;
    const int lr = lane & 15, lk = lane >> 4;

    short8 bw0[8], bw1[8], bw2[8];
    {
        const unsigned short* wb = Whh + ((size_t)(g*16 + lr))*NH + kh*256 + lk*8;
        #pragma unroll
        for (int ks=0; ks<8; ks++){
            bw0[ks] = *(const short8*)(wb + 0*262144 + ks*32);
            bw1[ks] = *(const short8*)(wb + 1*262144 + ks*32);
            bw2[ks] = *(const short8*)(wb + 2*262144 + ks*32);
        }
    }
    if (tid < 48) bhs[tid] = bhh[(tid>>4)*512 + g*16 + (tid&15)];
    for (int c = tid; c < NB*NS; c += 512) idx8[c] = (unsigned char)idx[c];

    // ---- step 0 (folded): this wg covers h in [g*16,g*16+16), all 64 batches ----
    for (int e = tid; e < NB*16; e += 512){
        int b = e >> 4, h = g*16 + (e & 15);
        const float* gr = gi + (size_t)b*NS*H3;
        float rr = sigmf(gr[h] + gh0[h]);
        float zz = sigmf(gr[512+h] + gh0[512+h]);
        float nn = tanhf(gr[1024+h] + rr*gh0[1024+h]);
        float v = (1.f-zz)*nn + zz*h0v[h];
        xf[(size_t)b*NS*NH + h] = v;
        unsigned short* xa = xb + (size_t)b*NS*NH + h;
        unsigned short pv = f2bf(v);
        asm volatile("global_store_short %0, %1, off sc0" :: "v"(xa), "v"(pv) : "memory");
    }
    asm volatile("s_waitcnt vmcnt(0)" ::: "memory");
    __syncthreads();
    if (tid == 0)
        __hip_atomic_fetch_add(myflag, 1, __ATOMIC_RELAXED, __HIP_MEMORY_SCOPE_AGENT);  // -> 1

    const int gb = tid >> 3, hp = tid & 7;
    const int hg = g*16 + hp*2;

    const int r0 = mgrp*32 + lr, r1 = r0 + 16;
    const int ab0 = r0 & 63, ab1 = r1 & 63;
    const int v0_ = r0 >> 6, v1_ = r1 >> 6;
    const bool pure2 = (mgrp >= 2);            // wave handles only hid2 rows

    int* const pollp = flagbase + (lane & 31)*32;

    float2 h1prev = make_float2(0.f, 0.f);
    {   // own (gb,hg) step-0 values: recompute locally (cheap, avoids visibility concerns)
        const float* gr = gi + (size_t)gb*NS*H3;
        float o[2];
        #pragma unroll
        for (int u=0;u<2;u++){
            int h = hg+u;
            float rr = sigmf(gr[h] + gh0[h]);
            float zz = sigmf(gr[512+h] + gh0[512+h]);
            float nn = tanhf(gr[1024+h] + rr*gh0[1024+h]);
            o[u] = (1.f-zz)*nn + zz*h0v[h];
        }
        h1prev = make_float2(o[0], o[1]);
    }
    float2 nx0 = *(const float2*)(gi + ((size_t)gb*NS + 1)*H3 + hg);
    float2 nx1 = *(const float2*)(gi + ((size_t)gb*NS + 1)*H3 + 512 + hg);
    float2 nx2 = *(const float2*)(gi + ((size_t)gb*NS + 1)*H3 + 1024 + hg);
    float2 nxA = *(const float2*)(alpha + ((size_t)gb*NS + 1)*2);

    bool earlyN = false;
    short8 a0[8], a1[8];

    for (int i = 1; i < NS; i++){
        // ---- hot poll: all wgs completed step i-1 (flags >= i) ----
        if (w == 0){
            int spins = 0;
            while (1){
                int v = __hip_atomic_load(pollp, __ATOMIC_RELAXED, __HIP_MEMORY_SCOPE_AGENT);
                if (__all(v >= i)) break;
                if (++spins > (1<<19)) break;
            }
        }
        __syncthreads();
        float2 cg0 = nx0, cg1 = nx1, cg2 = nx2, cA = nxA;
        if (!earlyN){
            int s0 = v0_ ? (int)idx8[ab0*NS + i] : (i-1);
            int s1 = v1_ ? (int)idx8[ab1*NS + i] : (i-1);
            const unsigned short* ap0 = xb + ((size_t)ab0*NS + s0)*NH + kh*256 + lk*8;
            const unsigned short* ap1 = xb + ((size_t)ab1*NS + s1)*NH + kh*256 + lk*8;
            LD16C(a0[0], ap0, "0");   LD16C(a0[1], ap0, "64");  LD16C(a0[2], ap0, "128"); LD16C(a0[3], ap0, "192");
            LD16C(a0[4], ap0, "256"); LD16C(a0[5], ap0, "320"); LD16C(a0[6], ap0, "384"); LD16C(a0[7], ap0, "448");
            LD16C(a1[0], ap1, "0");   LD16C(a1[1], ap1, "64");  LD16C(a1[2], ap1, "128"); LD16C(a1[3], ap1, "192");
            LD16C(a1[4], ap1, "256"); LD16C(a1[5], ap1, "320"); LD16C(a1[6], ap1, "384"); LD16C(a1[7], ap1, "448");
        }
        asm volatile("s_waitcnt vmcnt(0)" ::: "memory");
        __builtin_amdgcn_sched_barrier(0);
        f32x4 acc00 = {}, acc01 = {}, acc02 = {}, acc10 = {}, acc11 = {}, acc12 = {};
        #pragma unroll
        for (int ks=0; ks<8; ks++){
            acc00 = __builtin_amdgcn_mfma_f32_16x16x32_bf16(a0[ks], bw0[ks], acc00, 0,0,0);
            acc01 = __builtin_amdgcn_mfma_f32_16x16x32_bf16(a0[ks], bw1[ks], acc01, 0,0,0);
            acc02 = __builtin_amdgcn_mfma_f32_16x16x32_bf16(a0[ks], bw2[ks], acc02, 0,0,0);
            acc10 = __builtin_amdgcn_mfma_f32_16x16x32_bf16(a1[ks], bw0[ks], acc10, 0,0,0);
            acc11 = __builtin_amdgcn_mfma_f32_16x16x32_bf16(a1[ks], bw1[ks], acc11, 0,0,0);
            acc12 = __builtin_amdgcn_mfma_f32_16x16x32_bf16(a1[ks], bw2[ks], acc12, 0,0,0);
        }
        {
            int ip = (i+1 < NS) ? (i+1) : (NS-1);
            nx0 = *(const float2*)(gi + ((size_t)gb*NS + ip)*H3 + hg);
            nx1 = *(const float2*)(gi + ((size_t)gb*NS + ip)*H3 + 512 + hg);
            nx2 = *(const float2*)(gi + ((size_t)gb*NS + ip)*H3 + 1024 + hg);
            nxA = *(const float2*)(alpha + ((size_t)gb*NS + ip)*2);
        }
        #pragma unroll
        for (int j=0;j<4;j++){
            int m0 = mgrp*32 + lk*4 + j, m1 = m0 + 16;
            ghs[kh][m0][lr]    = acc00[j];
            ghs[kh][m0][16+lr] = acc01[j];
            ghs[kh][m0][32+lr] = acc02[j];
            ghs[kh][m1][lr]    = acc10[j];
            ghs[kh][m1][16+lr] = acc11[j];
            ghs[kh][m1][32+lr] = acc12[j];
        }
        __syncthreads();
        // ---- gate fusion ----
        {
            int rid = idx8[gb*NS + i];
            float2 h2p = *(const float2*)(xf + ((size_t)gb*NS + rid)*NH + hg);
            float o0, o1;
            #pragma unroll
            for (int u=0; u<2; u++){
                int hl = hp*2 + u;
                float g1r = ghs[0][gb][hl]       + ghs[1][gb][hl]       + bhs[hl];
                float g1z = ghs[0][gb][16+hl]    + ghs[1][gb][16+hl]    + bhs[16+hl];
                float g1n = ghs[0][gb][32+hl]    + ghs[1][gb][32+hl]    + bhs[32+hl];
                float g2r = ghs[0][64+gb][hl]    + ghs[1][64+gb][hl]    + bhs[hl];
                float g2z = ghs[0][64+gb][16+hl] + ghs[1][64+gb][16+hl] + bhs[16+hl];
                float g2n = ghs[0][64+gb][32+hl] + ghs[1][64+gb][32+hl] + bhs[32+hl];
                float ir  = u ? cg0.y : cg0.x;
                float iz  = u ? cg1.y : cg1.x;
                float inn = u ? cg2.y : cg2.x;
                float hh1 = u ? h1prev.y : h1prev.x;
                float hh2 = u ? h2p.y : h2p.x;
                float r1v = sigmf(ir + g1r), z1 = sigmf(iz + g1z);
                float n1 = tanhf(inn + r1v*g1n);
                float hid1 = (1.f-z1)*n1 + z1*hh1;
                float r2v = sigmf(ir + g2r), z2 = sigmf(iz + g2z);
                float n2 = tanhf(inn + r2v*g2n);
                float hid2 = (1.f-z2)*n2 + z2*hh2;
                float v = cA.x*hid1 + cA.y*hid2;
                if (u) o1 = v; else o0 = v;
            }
            *(float2*)(xf + ((size_t)gb*NS + i)*NH + hg) = make_float2(o0, o1);
            unsigned pk = (unsigned)f2bf(o0) | ((unsigned)f2bf(o1) << 16);
            unsigned short* xaddr = xb + ((size_t)gb*NS + i)*NH + hg;
            asm volatile("global_store_dword %0, %1, off sc0" :: "v"(xaddr), "v"(pk) : "memory");
            h1prev = make_float2(o0, o1);
        }
        asm volatile("s_waitcnt vmcnt(0)" ::: "memory");   // data committed to L2
        __syncthreads();
        if (tid == 0)
            __hip_atomic_fetch_add(myflag, 1, __ATOMIC_RELAXED, __HIP_MEMORY_SCOPE_AGENT);  // -> i+1
        // ---- early A-loads for step i+1 (pure-hid2 waves, rows <= i-1 already visible) ----
        earlyN = false;
        if (pure2 && (i+1 < NS)){
            int s0n = (int)idx8[ab0*NS + i+1];
            int s1n = (int)idx8[ab1*NS + i+1];
            if (__all((s0n <= i-1) && (s1n <= i-1))){
                earlyN = true;
                const unsigned short* ap0 = xb + ((size_t)ab0*NS + s0n)*NH + kh*256 + lk*8;
                const unsigned short* ap1 = xb + ((size_t)ab1*NS + s1n)*NH + kh*256 + lk*8;
                LD16C(a0[0], ap0, "0");   LD16C(a0[1], ap0, "64");  LD16C(a0[2], ap0, "128"); LD16C(a0[3], ap0, "192");
                LD16C(a0[4], ap0, "256"); LD16C(a0[5], ap0, "320"); LD16C(a0[6], ap0, "384"); LD16C(a0[7], ap0, "448");
                LD16C(a1[0], ap1, "0");   LD16C(a1[1], ap1, "64");  LD16C(a1[2], ap1, "128"); LD16C(a1[3], ap1, "192");
                LD16C(a1[4], ap1, "256"); LD16C(a1[5], ap1, "320"); LD16C(a1[6], ap1, "384"); LD16C(a1[7], ap1, "448");
            }
        }
    }
    if (tid == 0)
        __hip_atomic_fetch_add(&ctrl[11], 1, __ATOMIC_RELAXED, __HIP_MEMORY_SCOPE_AGENT);  // release keepers
}

// out_time: wave per row
__global__ void k_time(const float* __restrict__ xf, const float* __restrict__ W_time,
                       const float* __restrict__ b_time, float* __restrict__ out){
    int gw = (int)((blockIdx.x*(size_t)blockDim.x + threadIdx.x) >> 6);
    int lane = threadIdx.x & 63;
    if (gw >= NB*NS) return;
    const float* x = xf + (size_t)gw*NH;
    float s = 0.f;
    for (int k=lane;k<NH;k+=64) s += x[k]*W_time[k];
    for (int off=32; off; off>>=1) s += __shfl_down(s, off);
    if (lane == 0) out[gw] = s + b_time[0];
}

extern "C" void kernel_launch(void* const* d_in, const int* in_sizes, int n_in,
                              void* d_out, int out_size, void* d_ws, size_t ws_size,
                              hipStream_t stream){
    const float* src    = (const float*)d_in[0];
    const int*   lens   = (const int*)d_in[1];
    const int*   seq    = (const int*)d_in[2];
    const float* X      = (const float*)d_in[3];
    const float* A      = (const float*)d_in[4];
    const float* W_attn = (const float*)d_in[5];
    const float* a_attn = (const float*)d_in[6];
    const float* W_ih   = (const float*)d_in[7];
    const float* W_hh   = (const float*)d_in[8];
    const float* b_ih   = (const float*)d_in[9];
    const float* b_hh   = (const float*)d_in[10];
    const float* h0     = (const float*)d_in[11];
    const float* W_poi  = (const float*)d_in[12];
    const float* b_poi  = (const float*)d_in[13];
    const float* W_time = (const float*)d_in[14];
    const float* b_time = (const float*)d_in[15];
    const float* W_cat  = (const float*)d_in[16];
    const float* b_cat  = (const float*)d_in[17];

    char* ws = (char*)d_ws;
    float*          xf      = (float*)(ws + 0);                 // 16777216
    unsigned short* xb      = (unsigned short*)(ws + 16777216); // 8388608
    unsigned short* Whh_bf  = (unsigned short*)(ws + 25165824); // 1572864
    unsigned short* Wpoi_bf = (unsigned short*)(ws + 26738688); // 8388608
    unsigned short* Wcat_bf = (unsigned short*)(ws + 35127296); // 409600
    double*         wh1     = (double*)(ws + 35536896);         // 65536
    double*         wh2     = (double*)(ws + 35602432);         // 65536
    double*         c1d     = (double*)(ws + 35667968);         // 1024
    double*         c2d     = (double*)(ws + 35668992);         // 1024
    float*          alpha   = (float*)(ws + 35670016);          // 65536
    int*            idx     = (int*)(ws + 35735552);            // 32768
    float*          gh0     = (float*)(ws + 35768320);          // 6144
    int*            ctrl    = (int*)(ws + 35774464);            // cnt[8], winner[9], done[11], flags @+256

    char* ob = (char*)d_out;
    unsigned short* src_bf = (unsigned short*)(ob + 0);         // 8388608
    unsigned short* Wih_bf = (unsigned short*)(ob + 9437184);   // 1572864
    float*          gi     = (float*)(ob + 16777216);           // 50331648

    float* out_poi  = (float*)d_out;
    float* out_time = (float*)d_out + (size_t)8192*8192;
    float* out_cat  = out_time + 8192;

    k_zero<<<1, 512, 0, stream>>>(ctrl);
    k_cvt<<<4096, 256, 0, stream>>>(src, src_bf, NB*NS*NE);
    k_cvt<<<768, 256, 0, stream>>>(W_ih, Wih_bf, H3*NE);
    k_cvt<<<768, 256, 0, stream>>>(W_hh, Whh_bf, H3*NH);
    k_cvt<<<4096, 256, 0, stream>>>(W_poi, Wpoi_bf, NPOI_*NH);
    k_cvt<<<200, 256, 0, stream>>>(W_cat, Wcat_bf, NCAT_*NH);

    k_prep_c<<<1, 128, 0, stream>>>(W_attn, a_attn, c1d, c2d);
    k_wh<<<32, 256, 0, stream>>>(X, c1d, c2d, wh1, wh2);
    k_gh0<<<6, 256, 0, stream>>>(h0, W_hh, b_hh, gh0);
    k_attn<<<2048, 256, 0, stream>>>(seq, lens, A, wh1, wh2, alpha, idx);

    k_gemm_bf16<<<dim3(12, 64), 256, 0, stream>>>(src_bf, Wih_bf, b_ih, gi, NB*NS, H3, NE, H3);

    k_scan<<<NWG_LAUNCH, 512, 0, stream>>>(gi, Whh_bf, b_hh, alpha, idx, gh0, h0, xf, xb, ctrl);

    k_gemm_bf16<<<dim3(64, 64), 256, 0, stream>>>(xb, Wpoi_bf, b_poi, out_poi, NB*NS, NPOI_, NH, NPOI_);
    k_gemm_bf16<<<dim3(4, 64), 256, 0, stream>>>(xb, Wcat_bf, b_cat, out_cat, NB*NS, NCAT_, NH, NCAT_);
    k_time<<<2048, 256, 0, stream>>>(xf, W_time, b_time, out_time);
}

// Round 11
// 1027.646 us; speedup vs baseline: 1.9717x; 1.0724x over previous
//
#include <hip/hip_runtime.h>
#include <math.h>

typedef __attribute__((ext_vector_type(8))) short short8;
typedef __attribute__((ext_vector_type(4))) float f32x4;

#define NB 64
#define NS 128
#define NE 512
#define NH 512
#define NPOI_ 8192
#define NCAT_ 400
#define NF_ 128
#define H3 1536
#define NEGV -1000000000.0
#define GSZ 32
#define NWG_LAUNCH 256
#define LDT 88
#define NTILES (64*68)

// ws layout (bytes)
#define XF_OFF    0u
#define XB_OFF    16777216u
#define WHH_OFF   25165824u
#define WH1_OFF   26738688u
#define WH2_OFF   26804224u
#define C1_OFF    26869760u
#define C2_OFF    26870784u
#define AL_OFF    26871808u
#define IDX_OFF   26937344u
#define GH0_OFF   26970112u
#define CTRL_OFF  26976256u
#define WPOI_OFF  26984448u
#define WCAT_OFF  35373056u
#define GI_OFF    35782656u
#define WS_NEED   86114304u

__device__ inline float sigmf(float x){ return 1.0f/(1.0f + expf(-x)); }
__device__ inline unsigned short f2bf(float f){
    unsigned u = __float_as_uint(f);
    unsigned r = (u + 0x7fffu + ((u>>16)&1u)) >> 16;
    return (unsigned short)r;
}

// XCD-L2 load (scan-local data)
#define LD16C(d, p, o) asm volatile("global_load_dwordx4 %0, %1, off offset:" o " sc0" : "=&v"(d) : "v"(p))
// coherence-point load (cross-XCD consumer)
#define LD16G(d, p) asm volatile("global_load_dwordx4 %0, %1, off sc0 sc1" : "=&v"(d) : "v"(p))

__global__ void k_cvt(const float* __restrict__ in, unsigned short* __restrict__ out, int n){
    int t = blockIdx.x*blockDim.x + threadIdx.x;
    int i = t*4;
    if (i < n){
        float4 v = *(const float4*)(in + i);
        ushort4 o;
        o.x = f2bf(v.x); o.y = f2bf(v.y); o.z = f2bf(v.z); o.w = f2bf(v.w);
        *(ushort4*)(out + i) = o;
    }
}

__global__ void k_zero(int* p){
    for (int t = threadIdx.x; t < 2048; t += blockDim.x) p[t] = 0;
    __syncthreads();
    if (threadIdx.x == 0) p[9] = -1;
}

__global__ void k_prep_c(const float* __restrict__ W_attn, const float* __restrict__ a_attn,
                         double* __restrict__ c1d, double* __restrict__ c2d){
    int f = blockIdx.x*blockDim.x + threadIdx.x;
    if (f < NF_){
        double s1=0.0, s2=0.0;
        for (int k=0;k<NF_;k++){
            double w = (double)W_attn[f*NF_+k];
            s1 += w*(double)a_attn[k];
            s2 += w*(double)a_attn[NF_+k];
        }
        c1d[f]=s1; c2d[f]=s2;
    }
}

__global__ void k_wh(const float* __restrict__ X, const double* __restrict__ c1d,
                     const double* __restrict__ c2d, double* __restrict__ wh1, double* __restrict__ wh2){
    int p = blockIdx.x*blockDim.x + threadIdx.x;
    if (p < NPOI_){
        const float* x = X + (size_t)p*NF_;
        double s1=0.0,s2=0.0;
        for (int k=0;k<NF_;k++){ double xv=(double)x[k]; s1+=xv*c1d[k]; s2+=xv*c2d[k]; }
        wh1[p]=s1; wh2[p]=s2;
    }
}

__global__ void k_gh0(const float* __restrict__ h0, const float* __restrict__ W_hh,
                      const float* __restrict__ b_hh, float* __restrict__ gh0){
    int c = blockIdx.x*blockDim.x + threadIdx.x;
    if (c < H3){
        const float* w = W_hh + (size_t)c*NH;
        float s=0.f;
        for (int k=0;k<NH;k++) s += h0[k]*w[k];
        gh0[c] = s + b_hh[c];
    }
}

__device__ inline double shfl_down_d(double x, int off){
    long long v = __double_as_longlong(x);
    int lo = (int)(v & 0xffffffffLL), hi = (int)(((unsigned long long)v)>>32);
    lo = __shfl_down(lo, off); hi = __shfl_down(hi, off);
    return __longlong_as_double(((long long)hi<<32) | (unsigned long long)(unsigned int)lo);
}

__global__ void k_attn(const int* __restrict__ seq, const int* __restrict__ lens,
                       const float* __restrict__ A, const double* __restrict__ wh1,
                       const double* __restrict__ wh2, float* __restrict__ alpha,
                       int* __restrict__ idxout){
    int gw = (int)((blockIdx.x*(size_t)blockDim.x + threadIdx.x) >> 6);
    int lane = threadIdx.x & 63;
    if (gw >= NB*NS) return;
    int b = gw >> 7, j = gw & 127;
    int len = lens[b];
    int q = seq[b*NS + j];
    double wq = wh2[q];
    bool jvalid = (j < len);
    double mval = -1.0e300; int mk = 0;
    for (int k0=0;k0<NS;k0+=64){
        int k = k0 + lane;
        double val = NEGV;
        if (k < j && jvalid){
            int p = seq[b*NS + k];
            double e = wh1[p] + wq;
            e = (e > 0.0) ? e : 0.2*e;
            val = e * ((double)A[(size_t)p*NPOI_ + q] + 1.0);
        }
        if (val > mval){ mval = val; mk = k; }
    }
    for (int off=32; off; off>>=1){
        double ov = shfl_down_d(mval, off);
        int ok = __shfl_down(mk, off);
        if (ov > mval || (ov == mval && ok < mk)){ mval = ov; mk = ok; }
    }
    if (lane == 0){
        double v0 = mval;
        double v1;
        if (j == 0) v1 = 0.0;
        else if (!jvalid) v1 = NEGV;
        else {
            int p = seq[b*NS + j - 1];
            double e = wh1[p] + wq;
            e = (e > 0.0) ? e : 0.2*e;
            v1 = e * ((double)A[(size_t)p*NPOI_ + q] + 1.0);
        }
        double m = fmax(v0, v1);
        double e0 = exp(v0 - m), e1 = exp(v1 - m);
        double den = e0 + e1;
        alpha[(size_t)(b*NS+j)*2 + 0] = (float)(e0/den);
        alpha[(size_t)(b*NS+j)*2 + 1] = (float)(e1/den);
        idxout[b*NS + j] = mk;
    }
}

// classic NT GEMM (used for gi), XCD-swizzled
__global__ __launch_bounds__(256) void k_gemm_bf16(const unsigned short* __restrict__ A,
        const unsigned short* __restrict__ B, const float* __restrict__ bias,
        float* __restrict__ C, int M, int N, int K, int ldc){
    __shared__ unsigned short As[128][LDT];
    __shared__ unsigned short Bs[128][LDT];
    int nwg = gridDim.x*gridDim.y;
    int lin = blockIdx.y*gridDim.x + blockIdx.x;
    int l2 = (lin & 7)*(nwg >> 3) + (lin >> 3);
    int bm = l2 / gridDim.x, bn = l2 % gridDim.x;
    int row0 = bm*128, col0 = bn*128;
    int tid = threadIdx.x;
    int lane = tid & 63, w = tid >> 6;
    int wr = w >> 1, wc = w & 1;
    int lr = lane & 15, lk = lane >> 4;
    f32x4 acc[4][4] = {};
    for (int k0 = 0; k0 < K; k0 += 64){
        #pragma unroll
        for (int q = 0; q < 4; q++){
            int c = tid + 256*q;
            int r = c >> 3, ko = (c & 7)*8;
            *(short8*)&As[r][ko] = *(const short8*)(A + (size_t)(row0+r)*K + k0 + ko);
            int gc = col0 + r;
            short8 bv = {};
            if (gc < N) bv = *(const short8*)(B + (size_t)gc*K + k0 + ko);
            *(short8*)&Bs[r][ko] = bv;
        }
        __syncthreads();
        #pragma unroll
        for (int ks = 0; ks < 2; ks++){
            int kf = ks*32 + lk*8;
            short8 af[4], bf_[4];
            #pragma unroll
            for (int m=0;m<4;m++) af[m] = *(const short8*)&As[wr*64 + m*16 + lr][kf];
            #pragma unroll
            for (int n=0;n<4;n++) bf_[n] = *(const short8*)&Bs[wc*64 + n*16 + lr][kf];
            #pragma unroll
            for (int m=0;m<4;m++)
                #pragma unroll
                for (int n=0;n<4;n++)
                    acc[m][n] = __builtin_amdgcn_mfma_f32_16x16x32_bf16(af[m], bf_[n], acc[m][n], 0,0,0);
        }
        __syncthreads();
    }
    #pragma unroll
    for (int m=0;m<4;m++){
        #pragma unroll
        for (int n=0;n<4;n++){
            int col = col0 + wc*64 + n*16 + lr;
            if (col < N){
                float bb = bias[col];
                #pragma unroll
                for (int j=0;j<4;j++){
                    int row = row0 + wr*64 + m*16 + lk*4 + j;
                    C[(size_t)row*ldc + col] = acc[m][n][j] + bb;
                }
            }
        }
    }
}

// ---------- mega kernel: 32 winner wgs scan; 224 losers do flag-gated output GEMMs ----------
struct ScanSh {
    float ghs[2][128][50];
    unsigned char idx8[NB*NS];
    float bhs[48];
    int s_go, s_rank;
};
struct GemmSh {
    unsigned short As[128][LDT];
    unsigned short Bs[128][LDT];
    int tkt;
};

__global__ __launch_bounds__(512, 2) void k_mega(const float* __restrict__ gi,
        const unsigned short* __restrict__ Whh, const float* __restrict__ bhh,
        const float* __restrict__ alpha, const int* __restrict__ idx,
        const float* __restrict__ gh0, const float* __restrict__ h0v,
        float* __restrict__ xf, unsigned short* __restrict__ xb, int* __restrict__ ctrl,
        const unsigned short* __restrict__ Wpoi, const float* __restrict__ bpoi,
        const unsigned short* __restrict__ Wcat, const float* __restrict__ bcat,
        float* __restrict__ out_poi, float* __restrict__ out_cat, int overlap){
    __shared__ union { ScanSh S; GemmSh G; } U;
    const int tid = threadIdx.x;
    const int lane = tid & 63, w = tid >> 6;
    int* const flagbase = ctrl + 256;

    // ---- election ----
    if (tid == 0){
        int x;
        asm volatile("s_getreg_b32 %0, hwreg(HW_REG_XCC_ID)" : "=s"(x));
        x &= 7;
        int r = __hip_atomic_fetch_add(&ctrl[x], 1, __ATOMIC_RELAXED, __HIP_MEMORY_SCOPE_AGENT);
        int go = 0;
        if (r < GSZ){
            if (r == GSZ-1){
                int exp = -1;
                __hip_atomic_compare_exchange_strong(&ctrl[9], &exp, x,
                    __ATOMIC_RELAXED, __ATOMIC_RELAXED, __HIP_MEMORY_SCOPE_AGENT);
            }
            int spins = 0, wn;
            while ((wn = __hip_atomic_load(&ctrl[9], __ATOMIC_RELAXED, __HIP_MEMORY_SCOPE_AGENT)) == -1
                   && spins < (1<<20)){
                spins++;
                __builtin_amdgcn_s_sleep(1);
            }
            go = (wn == x);
        }
        U.S.s_go = go; U.S.s_rank = r;
    }
    __syncthreads();
    const int isScan = U.S.s_go;
    const int g = U.S.s_rank;
    __syncthreads();

    if (!isScan){
        // ================= GEMM worker =================
        const int wr = w >> 2, wc = w & 3;
        const int lr = lane & 15, lk = lane >> 4;
        const int c0 = tid, c1 = tid + 512;
        const int r0s = c0 >> 3, ko0 = (c0 & 7)*8;
        const int r1s = c1 >> 3, ko1 = (c1 & 7)*8;
        int* const pollp = flagbase + (lane & 31)*32;
        for (;;){
            if (tid == 0)
                U.G.tkt = __hip_atomic_fetch_add(&ctrl[12], 1, __ATOMIC_RELAXED, __HIP_MEMORY_SCOPE_AGENT);
            __syncthreads();
            int t = U.G.tkt;
            if (t >= NTILES) break;
            int m = t / 68, j = t % 68;
            int target = overlap ? (2*m + 2) : 128;
            const unsigned short* Bw; const float* bias; float* Cc; int ldc, Ncols, Nrows, col0;
            if (j < 64){ Bw = Wpoi; bias = bpoi; Cc = out_poi; ldc = NPOI_; Ncols = NPOI_; Nrows = NPOI_; col0 = j*128; }
            else       { Bw = Wcat; bias = bcat; Cc = out_cat; ldc = NCAT_; Ncols = NCAT_; Nrows = NCAT_; col0 = (j-64)*128; }
            // wait for positions to be final
            if (w == 0){
                int spins = 0;
                while (1){
                    int v = __hip_atomic_load(pollp, __ATOMIC_RELAXED, __HIP_MEMORY_SCOPE_AGENT);
                    if (__all(v >= target)) break;
                    if (++spins > (1<<20)) break;
                    __builtin_amdgcn_s_sleep(8);
                }
            }
            __syncthreads();
            // A row mapping (s-major): row' = m*128 + r ; b = r&63 ; s = 2m + (r>>6)
            const unsigned short* pa0 = xb + ((size_t)((r0s & 63)*128 + 2*m + (r0s >> 6)))*512 + ko0;
            const unsigned short* pa1 = xb + ((size_t)((r1s & 63)*128 + 2*m + (r1s >> 6)))*512 + ko1;
            f32x4 acc[4][2] = {};
            for (int k0 = 0; k0 < NH; k0 += 64){
                short8 a0v, a1v, b0v = {}, b1v = {};
                LD16G(a0v, pa0 + k0);
                LD16G(a1v, pa1 + k0);
                if (col0 + r0s < Nrows) b0v = *(const short8*)(Bw + (size_t)(col0 + r0s)*512 + k0 + ko0);
                if (col0 + r1s < Nrows) b1v = *(const short8*)(Bw + (size_t)(col0 + r1s)*512 + k0 + ko1);
                asm volatile("s_waitcnt vmcnt(0)" ::: "memory");
                *(short8*)&U.G.As[r0s][ko0] = a0v;
                *(short8*)&U.G.As[r1s][ko1] = a1v;
                *(short8*)&U.G.Bs[r0s][ko0] = b0v;
                *(short8*)&U.G.Bs[r1s][ko1] = b1v;
                __syncthreads();
                #pragma unroll
                for (int ks = 0; ks < 2; ks++){
                    int kf = ks*32 + lk*8;
                    short8 af[4], bfr[2];
                    #pragma unroll
                    for (int mi=0;mi<4;mi++) af[mi] = *(const short8*)&U.G.As[wr*64 + mi*16 + lr][kf];
                    #pragma unroll
                    for (int ni=0;ni<2;ni++) bfr[ni] = *(const short8*)&U.G.Bs[wc*32 + ni*16 + lr][kf];
                    #pragma unroll
                    for (int mi=0;mi<4;mi++)
                        #pragma unroll
                        for (int ni=0;ni<2;ni++)
                            acc[mi][ni] = __builtin_amdgcn_mfma_f32_16x16x32_bf16(af[mi], bfr[ni], acc[mi][ni], 0,0,0);
                }
                __syncthreads();
            }
            #pragma unroll
            for (int mi=0;mi<4;mi++){
                #pragma unroll
                for (int ni=0;ni<2;ni++){
                    int col = col0 + wc*32 + ni*16 + lr;
                    if (col < Ncols){
                        float bb = bias[col];
                        #pragma unroll
                        for (int jj=0;jj<4;jj++){
                            int rt = wr*64 + mi*16 + lk*4 + jj;
                            int row = (rt & 63)*128 + 2*m + (rt >> 6);
                            Cc[(size_t)row*ldc + col] = acc[mi][ni][jj] + bb;
                        }
                    }
                }
            }
        }
        return;
    }

    // ================= scan (r10 structure; xb stores write-through to LLC) =================
    int* const myflag = flagbase + g*32;
    const int kh = w & 1, mgrp = w >> 1;
    const int lr = lane & 15, lk = lane >> 4;

    short8 bw0[8], bw1[8], bw2[8];
    {
        const unsigned short* wb = Whh + ((size_t)(g*16 + lr))*NH + kh*256 + lk*8;
        #pragma unroll
        for (int ks=0; ks<8; ks++){
            bw0[ks] = *(const short8*)(wb + 0*262144 + ks*32);
            bw1[ks] = *(const short8*)(wb + 1*262144 + ks*32);
            bw2[ks] = *(const short8*)(wb + 2*262144 + ks*32);
        }
    }
    if (tid < 48) U.S.bhs[tid] = bhh[(tid>>4)*512 + g*16 + (tid&15)];
    for (int c = tid; c < NB*NS; c += 512) U.S.idx8[c] = (unsigned char)idx[c];

    // step 0 (folded)
    for (int e = tid; e < NB*16; e += 512){
        int b = e >> 4, h = g*16 + (e & 15);
        const float* gr = gi + (size_t)b*NS*H3;
        float rr = sigmf(gr[h] + gh0[h]);
        float zz = sigmf(gr[512+h] + gh0[512+h]);
        float nn = tanhf(gr[1024+h] + rr*gh0[1024+h]);
        float v = (1.f-zz)*nn + zz*h0v[h];
        xf[(size_t)b*NS*NH + h] = v;
        unsigned short* xa = xb + (size_t)b*NS*NH + h;
        unsigned short pv = f2bf(v);
        asm volatile("global_store_short %0, %1, off sc0 sc1" :: "v"(xa), "v"(pv) : "memory");
    }
    asm volatile("s_waitcnt vmcnt(0)" ::: "memory");
    __syncthreads();
    if (tid == 0)
        __hip_atomic_fetch_add(myflag, 1, __ATOMIC_RELAXED, __HIP_MEMORY_SCOPE_AGENT);

    const int gb = tid >> 3, hp = tid & 7;
    const int hg = g*16 + hp*2;
    const int r0 = mgrp*32 + lr, r1 = r0 + 16;
    const int ab0 = r0 & 63, ab1 = r1 & 63;
    const int v0_ = r0 >> 6, v1_ = r1 >> 6;
    const bool pure2 = (mgrp >= 2);
    int* const pollp = flagbase + (lane & 31)*32;

    float2 h1prev;
    {
        const float* gr = gi + (size_t)gb*NS*H3;
        float o[2];
        #pragma unroll
        for (int u=0;u<2;u++){
            int h = hg+u;
            float rr = sigmf(gr[h] + gh0[h]);
            float zz = sigmf(gr[512+h] + gh0[512+h]);
            float nn = tanhf(gr[1024+h] + rr*gh0[1024+h]);
            o[u] = (1.f-zz)*nn + zz*h0v[h];
        }
        h1prev = make_float2(o[0], o[1]);
    }
    float2 nx0 = *(const float2*)(gi + ((size_t)gb*NS + 1)*H3 + hg);
    float2 nx1 = *(const float2*)(gi + ((size_t)gb*NS + 1)*H3 + 512 + hg);
    float2 nx2 = *(const float2*)(gi + ((size_t)gb*NS + 1)*H3 + 1024 + hg);
    float2 nxA = *(const float2*)(alpha + ((size_t)gb*NS + 1)*2);

    bool earlyN = false;
    short8 a0[8], a1[8];

    for (int i = 1; i < NS; i++){
        if (w == 0){
            int spins = 0;
            while (1){
                int v = __hip_atomic_load(pollp, __ATOMIC_RELAXED, __HIP_MEMORY_SCOPE_AGENT);
                if (__all(v >= i)) break;
                if (++spins > (1<<19)) break;
            }
        }
        __syncthreads();
        float2 cg0 = nx0, cg1 = nx1, cg2 = nx2, cA = nxA;
        if (!earlyN){
            int s0 = v0_ ? (int)U.S.idx8[ab0*NS + i] : (i-1);
            int s1 = v1_ ? (int)U.S.idx8[ab1*NS + i] : (i-1);
            const unsigned short* ap0 = xb + ((size_t)ab0*NS + s0)*NH + kh*256 + lk*8;
            const unsigned short* ap1 = xb + ((size_t)ab1*NS + s1)*NH + kh*256 + lk*8;
            LD16C(a0[0], ap0, "0");   LD16C(a0[1], ap0, "64");  LD16C(a0[2], ap0, "128"); LD16C(a0[3], ap0, "192");
            LD16C(a0[4], ap0, "256"); LD16C(a0[5], ap0, "320"); LD16C(a0[6], ap0, "384"); LD16C(a0[7], ap0, "448");
            LD16C(a1[0], ap1, "0");   LD16C(a1[1], ap1, "64");  LD16C(a1[2], ap1, "128"); LD16C(a1[3], ap1, "192");
            LD16C(a1[4], ap1, "256"); LD16C(a1[5], ap1, "320"); LD16C(a1[6], ap1, "384"); LD16C(a1[7], ap1, "448");
        }
        asm volatile("s_waitcnt vmcnt(0)" ::: "memory");
        __builtin_amdgcn_sched_barrier(0);
        f32x4 acc00 = {}, acc01 = {}, acc02 = {}, acc10 = {}, acc11 = {}, acc12 = {};
        #pragma unroll
        for (int ks=0; ks<8; ks++){
            acc00 = __builtin_amdgcn_mfma_f32_16x16x32_bf16(a0[ks], bw0[ks], acc00, 0,0,0);
            acc01 = __builtin_amdgcn_mfma_f32_16x16x32_bf16(a0[ks], bw1[ks], acc01, 0,0,0);
            acc02 = __builtin_amdgcn_mfma_f32_16x16x32_bf16(a0[ks], bw2[ks], acc02, 0,0,0);
            acc10 = __builtin_amdgcn_mfma_f32_16x16x32_bf16(a1[ks], bw0[ks], acc10, 0,0,0);
            acc11 = __builtin_amdgcn_mfma_f32_16x16x32_bf16(a1[ks], bw1[ks], acc11, 0,0,0);
            acc12 = __builtin_amdgcn_mfma_f32_16x16x32_bf16(a1[ks], bw2[ks], acc12, 0,0,0);
        }
        {
            int ip = (i+1 < NS) ? (i+1) : (NS-1);
            nx0 = *(const float2*)(gi + ((size_t)gb*NS + ip)*H3 + hg);
            nx1 = *(const float2*)(gi + ((size_t)gb*NS + ip)*H3 + 512 + hg);
            nx2 = *(const float2*)(gi + ((size_t)gb*NS + ip)*H3 + 1024 + hg);
            nxA = *(const float2*)(alpha + ((size_t)gb*NS + ip)*2);
        }
        #pragma unroll
        for (int j=0;j<4;j++){
            int m0 = mgrp*32 + lk*4 + j, m1 = m0 + 16;
            U.S.ghs[kh][m0][lr]    = acc00[j];
            U.S.ghs[kh][m0][16+lr] = acc01[j];
            U.S.ghs[kh][m0][32+lr] = acc02[j];
            U.S.ghs[kh][m1][lr]    = acc10[j];
            U.S.ghs[kh][m1][16+lr] = acc11[j];
            U.S.ghs[kh][m1][32+lr] = acc12[j];
        }
        __syncthreads();
        {
            int rid = U.S.idx8[gb*NS + i];
            float2 h2p = *(const float2*)(xf + ((size_t)gb*NS + rid)*NH + hg);
            float o0, o1;
            #pragma unroll
            for (int u=0; u<2; u++){
                int hl = hp*2 + u;
                float g1r = U.S.ghs[0][gb][hl]       + U.S.ghs[1][gb][hl]       + U.S.bhs[hl];
                float g1z = U.S.ghs[0][gb][16+hl]    + U.S.ghs[1][gb][16+hl]    + U.S.bhs[16+hl];
                float g1n = U.S.ghs[0][gb][32+hl]    + U.S.ghs[1][gb][32+hl]    + U.S.bhs[32+hl];
                float g2r = U.S.ghs[0][64+gb][hl]    + U.S.ghs[1][64+gb][hl]    + U.S.bhs[hl];
                float g2z = U.S.ghs[0][64+gb][16+hl] + U.S.ghs[1][64+gb][16+hl] + U.S.bhs[16+hl];
                float g2n = U.S.ghs[0][64+gb][32+hl] + U.S.ghs[1][64+gb][32+hl] + U.S.bhs[32+hl];
                float ir  = u ? cg0.y : cg0.x;
                float iz  = u ? cg1.y : cg1.x;
                float inn = u ? cg2.y : cg2.x;
                float hh1 = u ? h1prev.y : h1prev.x;
                float hh2 = u ? h2p.y : h2p.x;
                float r1v = sigmf(ir + g1r), z1 = sigmf(iz + g1z);
                float n1 = tanhf(inn + r1v*g1n);
                float hid1 = (1.f-z1)*n1 + z1*hh1;
                float r2v = sigmf(ir + g2r), z2 = sigmf(iz + g2z);
                float n2 = tanhf(inn + r2v*g2n);
                float hid2 = (1.f-z2)*n2 + z2*hh2;
                float v = cA.x*hid1 + cA.y*hid2;
                if (u) o1 = v; else o0 = v;
            }
            *(float2*)(xf + ((size_t)gb*NS + i)*NH + hg) = make_float2(o0, o1);
            unsigned pk = (unsigned)f2bf(o0) | ((unsigned)f2bf(o1) << 16);
            unsigned short* xaddr = xb + ((size_t)gb*NS + i)*NH + hg;
            asm volatile("global_store_dword %0, %1, off sc0 sc1" :: "v"(xaddr), "v"(pk) : "memory");
            h1prev = make_float2(o0, o1);
        }
        asm volatile("s_waitcnt vmcnt(0)" ::: "memory");
        __syncthreads();
        if (tid == 0)
            __hip_atomic_fetch_add(myflag, 1, __ATOMIC_RELAXED, __HIP_MEMORY_SCOPE_AGENT);
        earlyN = false;
        if (pure2 && (i+1 < NS)){
            int s0n = (int)U.S.idx8[ab0*NS + i+1];
            int s1n = (int)U.S.idx8[ab1*NS + i+1];
            if (__all((s0n <= i-1) && (s1n <= i-1))){
                earlyN = true;
                const unsigned short* ap0 = xb + ((size_t)ab0*NS + s0n)*NH + kh*256 + lk*8;
                const unsigned short* ap1 = xb + ((size_t)ab1*NS + s1n)*NH + kh*256 + lk*8;
                LD16C(a0[0], ap0, "0");   LD16C(a0[1], ap0, "64");  LD16C(a0[2], ap0, "128"); LD16C(a0[3], ap0, "192");
                LD16C(a0[4], ap0, "256"); LD16C(a0[5], ap0, "320"); LD16C(a0[6], ap0, "384"); LD16C(a0[7], ap0, "448");
                LD16C(a1[0], ap1, "0");   LD16C(a1[1], ap1, "64");  LD16C(a1[2], ap1, "128"); LD16C(a1[3], ap1, "192");
                LD16C(a1[4], ap1, "256"); LD16C(a1[5], ap1, "320"); LD16C(a1[6], ap1, "384"); LD16C(a1[7], ap1, "448");
            }
        }
    }
}

__global__ void k_time(const float* __restrict__ xf, const float* __restrict__ W_time,
                       const float* __restrict__ b_time, float* __restrict__ out){
    int gw = (int)((blockIdx.x*(size_t)blockDim.x + threadIdx.x) >> 6);
    int lane = threadIdx.x & 63;
    if (gw >= NB*NS) return;
    const float* x = xf + (size_t)gw*NH;
    float s = 0.f;
    for (int k=lane;k<NH;k+=64) s += x[k]*W_time[k];
    for (int off=32; off; off>>=1) s += __shfl_down(s, off);
    if (lane == 0) out[gw] = s + b_time[0];
}

extern "C" void kernel_launch(void* const* d_in, const int* in_sizes, int n_in,
                              void* d_out, int out_size, void* d_ws, size_t ws_size,
                              hipStream_t stream){
    const float* src    = (const float*)d_in[0];
    const int*   lens   = (const int*)d_in[1];
    const int*   seq    = (const int*)d_in[2];
    const float* X      = (const float*)d_in[3];
    const float* A      = (const float*)d_in[4];
    const float* W_attn = (const float*)d_in[5];
    const float* a_attn = (const float*)d_in[6];
    const float* W_ih   = (const float*)d_in[7];
    const float* W_hh   = (const float*)d_in[8];
    const float* b_ih   = (const float*)d_in[9];
    const float* b_hh   = (const float*)d_in[10];
    const float* h0     = (const float*)d_in[11];
    const float* W_poi  = (const float*)d_in[12];
    const float* b_poi  = (const float*)d_in[13];
    const float* W_time = (const float*)d_in[14];
    const float* b_time = (const float*)d_in[15];
    const float* W_cat  = (const float*)d_in[16];
    const float* b_cat  = (const float*)d_in[17];

    char* ws = (char*)d_ws;
    float*          xf      = (float*)(ws + XF_OFF);
    unsigned short* xb      = (unsigned short*)(ws + XB_OFF);
    unsigned short* Whh_bf  = (unsigned short*)(ws + WHH_OFF);
    double*         wh1     = (double*)(ws + WH1_OFF);
    double*         wh2     = (double*)(ws + WH2_OFF);
    double*         c1d     = (double*)(ws + C1_OFF);
    double*         c2d     = (double*)(ws + C2_OFF);
    float*          alpha   = (float*)(ws + AL_OFF);
    int*            idx     = (int*)(ws + IDX_OFF);
    float*          gh0     = (float*)(ws + GH0_OFF);
    int*            ctrl    = (int*)(ws + CTRL_OFF);
    unsigned short* Wpoi_bf = (unsigned short*)(ws + WPOI_OFF);
    unsigned short* Wcat_bf = (unsigned short*)(ws + WCAT_OFF);

    int overlap = (ws_size >= (size_t)WS_NEED) ? 1 : 0;

    char* ob = (char*)d_out;
    unsigned short* src_bf = (unsigned short*)(ob + 0);         // dead before C writes
    unsigned short* Wih_bf = (unsigned short*)(ob + 9437184);
    float* gi = overlap ? (float*)(ws + GI_OFF) : (float*)(ob + 16777216);

    float* out_poi  = (float*)d_out;
    float* out_time = (float*)d_out + (size_t)8192*8192;
    float* out_cat  = out_time + 8192;

    k_zero<<<1, 512, 0, stream>>>(ctrl);
    k_cvt<<<4096, 256, 0, stream>>>(src, src_bf, NB*NS*NE);
    k_cvt<<<768, 256, 0, stream>>>(W_ih, Wih_bf, H3*NE);
    k_cvt<<<768, 256, 0, stream>>>(W_hh, Whh_bf, H3*NH);
    k_cvt<<<4096, 256, 0, stream>>>(W_poi, Wpoi_bf, NPOI_*NH);
    k_cvt<<<200, 256, 0, stream>>>(W_cat, Wcat_bf, NCAT_*NH);

    k_prep_c<<<1, 128, 0, stream>>>(W_attn, a_attn, c1d, c2d);
    k_wh<<<32, 256, 0, stream>>>(X, c1d, c2d, wh1, wh2);
    k_gh0<<<6, 256, 0, stream>>>(h0, W_hh, b_hh, gh0);
    k_attn<<<2048, 256, 0, stream>>>(seq, lens, A, wh1, wh2, alpha, idx);

    k_gemm_bf16<<<dim3(12, 64), 256, 0, stream>>>(src_bf, Wih_bf, b_ih, gi, NB*NS, H3, NE, H3);

    k_mega<<<NWG_LAUNCH, 512, 0, stream>>>(gi, Whh_bf, b_hh, alpha, idx, gh0, h0,
                                           xf, xb, ctrl, Wpoi_bf, b_poi, Wcat_bf, b_cat,
                                           out_poi, out_cat, overlap);

    k_time<<<2048, 256, 0, stream>>>(xf, W_time, b_time, out_time);
}

// Round 12
// 961.808 us; speedup vs baseline: 2.1067x; 1.0685x over previous
//
#include <hip/hip_runtime.h>
#include <math.h>

typedef __attribute__((ext_vector_type(8))) short short8;
typedef __attribute__((ext_vector_type(4))) float f32x4;

#define NB 64
#define NS 128
#define NE 512
#define NH 512
#define NPOI_ 8192
#define NCAT_ 400
#define NF_ 128
#define H3 1536
#define NEGV -1000000000.0
#define GSZ 32
#define NWG_LAUNCH 256
#define LDT 88
#define NTILES (64*68)

// ws layout (bytes)
#define XF_OFF    0u
#define XB_OFF    16777216u
#define WHH_OFF   25165824u
#define WH1_OFF   26738688u
#define WH2_OFF   26804224u
#define AL_OFF    26871808u
#define IDX_OFF   26937344u
#define GH0_OFF   26970112u
#define CTRL_OFF  26976256u
#define WPOI_OFF  26984448u
#define WCAT_OFF  35373056u
#define GI_OFF    35782656u
#define WS_NEED   86114304u
#define XB2_OFF   86114304u
#define WS_NEED2  94502912u

__device__ inline float sigmf(float x){ return 1.0f/(1.0f + expf(-x)); }
__device__ inline unsigned short f2bf(float f){
    unsigned u = __float_as_uint(f);
    unsigned r = (u + 0x7fffu + ((u>>16)&1u)) >> 16;
    return (unsigned short)r;
}

// XCD-L2 load (scan-local data)
#define LD16C(d, p, o) asm volatile("global_load_dwordx4 %0, %1, off offset:" o " sc0" : "=&v"(d) : "v"(p))
// coherence-point load (cross-XCD consumer)
#define LD16G(d, p) asm volatile("global_load_dwordx4 %0, %1, off sc0 sc1" : "=&v"(d) : "v"(p))

// ---------- merged init: ctrl clear + all f32->bf16 conversions ----------
__global__ void k_init(int* ctrl,
        const float* __restrict__ s0, unsigned short* __restrict__ d0,
        const float* __restrict__ s1, unsigned short* __restrict__ d1,
        const float* __restrict__ s2, unsigned short* __restrict__ d2,
        const float* __restrict__ s3, unsigned short* __restrict__ d3,
        const float* __restrict__ s4, unsigned short* __restrict__ d4){
    if (blockIdx.x == 0){
        for (int t = threadIdx.x; t < 2048; t += blockDim.x) ctrl[t] = 0;
        __syncthreads();
        if (threadIdx.x == 0) ctrl[9] = -1;
    }
    const int Q0=1048576, Q1=196608, Q2=196608, Q3=1048576, Q4=51200;
    const int total = Q0+Q1+Q2+Q3+Q4;
    for (int q = blockIdx.x*blockDim.x + threadIdx.x; q < total; q += gridDim.x*blockDim.x){
        const float* sp; unsigned short* dp; int o;
        if (q < Q0){ sp=s0; dp=d0; o=q; }
        else if (q < Q0+Q1){ sp=s1; dp=d1; o=q-Q0; }
        else if (q < Q0+Q1+Q2){ sp=s2; dp=d2; o=q-Q0-Q1; }
        else if (q < Q0+Q1+Q2+Q3){ sp=s3; dp=d3; o=q-Q0-Q1-Q2; }
        else { sp=s4; dp=d4; o=q-Q0-Q1-Q2-Q3; }
        float4 v = *(const float4*)(sp + (size_t)o*4);
        ushort4 u;
        u.x=f2bf(v.x); u.y=f2bf(v.y); u.z=f2bf(v.z); u.w=f2bf(v.w);
        *(ushort4*)(dp + (size_t)o*4) = u;
    }
}

// ---------- merged: c1/c2 (per-block, f64) + wh + gh0 ----------
__global__ void k_wh(const float* __restrict__ X, const float* __restrict__ W_attn,
                     const float* __restrict__ a_attn, double* __restrict__ wh1,
                     double* __restrict__ wh2, const float* __restrict__ h0,
                     const float* __restrict__ W_hh, const float* __restrict__ b_hh,
                     float* __restrict__ gh0){
    int blk = blockIdx.x, tid = threadIdx.x;
    if (blk >= 32){
        int c = (blk-32)*256 + tid;
        if (c < H3){
            const float* w = W_hh + (size_t)c*NH;
            float s=0.f;
            for (int k=0;k<NH;k++) s += h0[k]*w[k];
            gh0[c] = s + b_hh[c];
        }
        return;
    }
    __shared__ double c1s[128], c2s[128];
    if (tid < 128){
        double s1=0.0, s2=0.0;
        for (int k=0;k<NF_;k++){
            double w = (double)W_attn[tid*NF_+k];
            s1 += w*(double)a_attn[k];
            s2 += w*(double)a_attn[NF_+k];
        }
        c1s[tid]=s1; c2s[tid]=s2;
    }
    __syncthreads();
    int p = blk*256 + tid;
    const float* x = X + (size_t)p*NF_;
    double s1=0.0, s2=0.0;
    for (int k=0;k<NF_;k++){ double xv=(double)x[k]; s1+=xv*c1s[k]; s2+=xv*c2s[k]; }
    wh1[p]=s1; wh2[p]=s2;
}

__device__ inline double shfl_down_d(double x, int off){
    long long v = __double_as_longlong(x);
    int lo = (int)(v & 0xffffffffLL), hi = (int)(((unsigned long long)v)>>32);
    lo = __shfl_down(lo, off); hi = __shfl_down(hi, off);
    return __longlong_as_double(((long long)hi<<32) | (unsigned long long)(unsigned int)lo);
}

__global__ void k_attn(const int* __restrict__ seq, const int* __restrict__ lens,
                       const float* __restrict__ A, const double* __restrict__ wh1,
                       const double* __restrict__ wh2, float* __restrict__ alpha,
                       int* __restrict__ idxout){
    int gw = (int)((blockIdx.x*(size_t)blockDim.x + threadIdx.x) >> 6);
    int lane = threadIdx.x & 63;
    if (gw >= NB*NS) return;
    int b = gw >> 7, j = gw & 127;
    int len = lens[b];
    int q = seq[b*NS + j];
    double wq = wh2[q];
    bool jvalid = (j < len);
    double mval = -1.0e300; int mk = 0;
    for (int k0=0;k0<NS;k0+=64){
        int k = k0 + lane;
        double val = NEGV;
        if (k < j && jvalid){
            int p = seq[b*NS + k];
            double e = wh1[p] + wq;
            e = (e > 0.0) ? e : 0.2*e;
            val = e * ((double)A[(size_t)p*NPOI_ + q] + 1.0);
        }
        if (val > mval){ mval = val; mk = k; }
    }
    for (int off=32; off; off>>=1){
        double ov = shfl_down_d(mval, off);
        int ok = __shfl_down(mk, off);
        if (ov > mval || (ov == mval && ok < mk)){ mval = ov; mk = ok; }
    }
    if (lane == 0){
        double v0 = mval;
        double v1;
        if (j == 0) v1 = 0.0;
        else if (!jvalid) v1 = NEGV;
        else {
            int p = seq[b*NS + j - 1];
            double e = wh1[p] + wq;
            e = (e > 0.0) ? e : 0.2*e;
            v1 = e * ((double)A[(size_t)p*NPOI_ + q] + 1.0);
        }
        double m = fmax(v0, v1);
        double e0 = exp(v0 - m), e1 = exp(v1 - m);
        double den = e0 + e1;
        alpha[(size_t)(b*NS+j)*2 + 0] = (float)(e0/den);
        alpha[(size_t)(b*NS+j)*2 + 1] = (float)(e1/den);
        idxout[b*NS + j] = mk;
    }
}

// classic NT GEMM (used for gi), XCD-swizzled
__global__ __launch_bounds__(256) void k_gemm_bf16(const unsigned short* __restrict__ A,
        const unsigned short* __restrict__ B, const float* __restrict__ bias,
        float* __restrict__ C, int M, int N, int K, int ldc){
    __shared__ unsigned short As[128][LDT];
    __shared__ unsigned short Bs[128][LDT];
    int nwg = gridDim.x*gridDim.y;
    int lin = blockIdx.y*gridDim.x + blockIdx.x;
    int l2 = (lin & 7)*(nwg >> 3) + (lin >> 3);
    int bm = l2 / gridDim.x, bn = l2 % gridDim.x;
    int row0 = bm*128, col0 = bn*128;
    int tid = threadIdx.x;
    int lane = tid & 63, w = tid >> 6;
    int wr = w >> 1, wc = w & 1;
    int lr = lane & 15, lk = lane >> 4;
    f32x4 acc[4][4] = {};
    for (int k0 = 0; k0 < K; k0 += 64){
        #pragma unroll
        for (int q = 0; q < 4; q++){
            int c = tid + 256*q;
            int r = c >> 3, ko = (c & 7)*8;
            *(short8*)&As[r][ko] = *(const short8*)(A + (size_t)(row0+r)*K + k0 + ko);
            int gc = col0 + r;
            short8 bv = {};
            if (gc < N) bv = *(const short8*)(B + (size_t)gc*K + k0 + ko);
            *(short8*)&Bs[r][ko] = bv;
        }
        __syncthreads();
        #pragma unroll
        for (int ks = 0; ks < 2; ks++){
            int kf = ks*32 + lk*8;
            short8 af[4], bf_[4];
            #pragma unroll
            for (int m=0;m<4;m++) af[m] = *(const short8*)&As[wr*64 + m*16 + lr][kf];
            #pragma unroll
            for (int n=0;n<4;n++) bf_[n] = *(const short8*)&Bs[wc*64 + n*16 + lr][kf];
            #pragma unroll
            for (int m=0;m<4;m++)
                #pragma unroll
                for (int n=0;n<4;n++)
                    acc[m][n] = __builtin_amdgcn_mfma_f32_16x16x32_bf16(af[m], bf_[n], acc[m][n], 0,0,0);
        }
        __syncthreads();
    }
    #pragma unroll
    for (int m=0;m<4;m++){
        #pragma unroll
        for (int n=0;n<4;n++){
            int col = col0 + wc*64 + n*16 + lr;
            if (col < N){
                float bb = bias[col];
                #pragma unroll
                for (int j=0;j<4;j++){
                    int row = row0 + wr*64 + m*16 + lk*4 + j;
                    C[(size_t)row*ldc + col] = acc[m][n][j] + bb;
                }
            }
        }
    }
}

// ---------- mega kernel ----------
struct ScanSh {
    float ghs[2][128][50];
    unsigned char idx8[NB*NS];
    float bhs[48];
    int s_go, s_rank;
};
struct GemmSh {
    unsigned short As[128][LDT];
    unsigned short Bs[128][LDT];
    int tkt;
};

__global__ __launch_bounds__(512, 2) void k_mega(const float* __restrict__ gi,
        const unsigned short* __restrict__ Whh, const float* __restrict__ bhh,
        const float* __restrict__ alpha, const int* __restrict__ idx,
        const float* __restrict__ gh0, const float* __restrict__ h0v,
        float* __restrict__ xf, unsigned short* __restrict__ xb,
        unsigned short* __restrict__ xb2, int* __restrict__ ctrl,
        const unsigned short* __restrict__ Wpoi, const float* __restrict__ bpoi,
        const unsigned short* __restrict__ Wcat, const float* __restrict__ bcat,
        float* __restrict__ out_poi, float* __restrict__ out_cat, int overlap){
    __shared__ union { ScanSh S; GemmSh G; } U;
    const int tid = threadIdx.x;
    const int lane = tid & 63, w = tid >> 6;
    int* const flagbase = ctrl + 256;
    int* const progp = ctrl + 128;     // progress mirror, own cache line

    // ---- election ----
    if (tid == 0){
        int x;
        asm volatile("s_getreg_b32 %0, hwreg(HW_REG_XCC_ID)" : "=s"(x));
        x &= 7;
        int r = __hip_atomic_fetch_add(&ctrl[x], 1, __ATOMIC_RELAXED, __HIP_MEMORY_SCOPE_AGENT);
        int go = 0;
        if (r < GSZ){
            if (r == GSZ-1){
                int exp = -1;
                __hip_atomic_compare_exchange_strong(&ctrl[9], &exp, x,
                    __ATOMIC_RELAXED, __ATOMIC_RELAXED, __HIP_MEMORY_SCOPE_AGENT);
            }
            int spins = 0, wn;
            while ((wn = __hip_atomic_load(&ctrl[9], __ATOMIC_RELAXED, __HIP_MEMORY_SCOPE_AGENT)) == -1
                   && spins < (1<<20)){
                spins++;
                __builtin_amdgcn_s_sleep(1);
            }
            go = (wn == x);
        }
        U.S.s_go = go; U.S.s_rank = r;
    }
    __syncthreads();
    const int isScan = U.S.s_go;
    const int g = U.S.s_rank;
    __syncthreads();

    if (!isScan){
        // ================= GEMM worker (polls progress mirror only) =================
        const int wr = w >> 2, wc = w & 3;
        const int lr = lane & 15, lk = lane >> 4;
        const int c0 = tid, c1 = tid + 512;
        const int r0s = c0 >> 3, ko0 = (c0 & 7)*8;
        const int r1s = c1 >> 3, ko1 = (c1 & 7)*8;
        for (;;){
            if (tid == 0)
                U.G.tkt = __hip_atomic_fetch_add(&ctrl[12], 1, __ATOMIC_RELAXED, __HIP_MEMORY_SCOPE_AGENT);
            __syncthreads();
            int t = U.G.tkt;
            if (t >= NTILES) break;
            int m = t / 68, j = t % 68;
            int target = overlap ? (2*m + 2) : NS;
            const unsigned short* Bw; const float* bias; float* Cc; int ldc, Ncols, Nrows, col0;
            if (j < 64){ Bw = Wpoi; bias = bpoi; Cc = out_poi; ldc = NPOI_; Ncols = NPOI_; Nrows = NPOI_; col0 = j*128; }
            else       { Bw = Wcat; bias = bcat; Cc = out_cat; ldc = NCAT_; Ncols = NCAT_; Nrows = NCAT_; col0 = (j-64)*128; }
            if (tid == 0){
                int spins = 0;
                while (__hip_atomic_load(progp, __ATOMIC_RELAXED, __HIP_MEMORY_SCOPE_AGENT) < target
                       && spins < (1<<22)){
                    spins++;
                    __builtin_amdgcn_s_sleep(4);
                }
            }
            __syncthreads();
            const unsigned short* pa0 = xb2 + ((size_t)((r0s & 63)*128 + 2*m + (r0s >> 6)))*512 + ko0;
            const unsigned short* pa1 = xb2 + ((size_t)((r1s & 63)*128 + 2*m + (r1s >> 6)))*512 + ko1;
            f32x4 acc[4][2] = {};
            for (int k0 = 0; k0 < NH; k0 += 64){
                short8 a0v, a1v, b0v = {}, b1v = {};
                LD16G(a0v, pa0 + k0);
                LD16G(a1v, pa1 + k0);
                if (col0 + r0s < Nrows) b0v = *(const short8*)(Bw + (size_t)(col0 + r0s)*512 + k0 + ko0);
                if (col0 + r1s < Nrows) b1v = *(const short8*)(Bw + (size_t)(col0 + r1s)*512 + k0 + ko1);
                asm volatile("s_waitcnt vmcnt(0)" ::: "memory");
                *(short8*)&U.G.As[r0s][ko0] = a0v;
                *(short8*)&U.G.As[r1s][ko1] = a1v;
                *(short8*)&U.G.Bs[r0s][ko0] = b0v;
                *(short8*)&U.G.Bs[r1s][ko1] = b1v;
                __syncthreads();
                #pragma unroll
                for (int ks = 0; ks < 2; ks++){
                    int kf = ks*32 + lk*8;
                    short8 af[4], bfr[2];
                    #pragma unroll
                    for (int mi=0;mi<4;mi++) af[mi] = *(const short8*)&U.G.As[wr*64 + mi*16 + lr][kf];
                    #pragma unroll
                    for (int ni=0;ni<2;ni++) bfr[ni] = *(const short8*)&U.G.Bs[wc*32 + ni*16 + lr][kf];
                    #pragma unroll
                    for (int mi=0;mi<4;mi++)
                        #pragma unroll
                        for (int ni=0;ni<2;ni++)
                            acc[mi][ni] = __builtin_amdgcn_mfma_f32_16x16x32_bf16(af[mi], bfr[ni], acc[mi][ni], 0,0,0);
                }
                __syncthreads();
            }
            #pragma unroll
            for (int mi=0;mi<4;mi++){
                #pragma unroll
                for (int ni=0;ni<2;ni++){
                    int col = col0 + wc*32 + ni*16 + lr;
                    if (col < Ncols){
                        float bb = bias[col];
                        #pragma unroll
                        for (int jj=0;jj<4;jj++){
                            int rt = wr*64 + mi*16 + lk*4 + jj;
                            int row = (rt & 63)*128 + 2*m + (rt >> 6);
                            Cc[(size_t)row*ldc + col] = acc[mi][ni][jj] + bb;
                        }
                    }
                }
            }
        }
        return;
    }

    // ================= scan =================
    int* const myflag = flagbase + g*32;
    const int kh = w & 1, mgrp = w >> 1;
    const int lr = lane & 15, lk = lane >> 4;

    short8 bw0[8], bw1[8], bw2[8];
    {
        const unsigned short* wb = Whh + ((size_t)(g*16 + lr))*NH + kh*256 + lk*8;
        #pragma unroll
        for (int ks=0; ks<8; ks++){
            bw0[ks] = *(const short8*)(wb + 0*262144 + ks*32);
            bw1[ks] = *(const short8*)(wb + 1*262144 + ks*32);
            bw2[ks] = *(const short8*)(wb + 2*262144 + ks*32);
        }
    }
    if (tid < 48) U.S.bhs[tid] = bhh[(tid>>4)*512 + g*16 + (tid&15)];
    for (int c = tid; c < NB*NS; c += 512) U.S.idx8[c] = (unsigned char)idx[c];

    // step 0 (folded): dual store (local + LLC copy)
    for (int e = tid; e < NB*16; e += 512){
        int b = e >> 4, h = g*16 + (e & 15);
        const float* gr = gi + (size_t)b*NS*H3;
        float rr = sigmf(gr[h] + gh0[h]);
        float zz = sigmf(gr[512+h] + gh0[512+h]);
        float nn = tanhf(gr[1024+h] + rr*gh0[1024+h]);
        float v = (1.f-zz)*nn + zz*h0v[h];
        xf[(size_t)b*NS*NH + h] = v;
        unsigned short pv = f2bf(v);
        unsigned short* xa  = xb  + (size_t)b*NS*NH + h;
        unsigned short* xa2 = xb2 + (size_t)b*NS*NH + h;
        asm volatile("global_store_short %0, %1, off sc0" :: "v"(xa), "v"(pv) : "memory");
        asm volatile("global_store_short %0, %1, off sc0 sc1" :: "v"(xa2), "v"(pv) : "memory");
    }
    asm volatile("s_waitcnt vmcnt(0)" ::: "memory");
    __syncthreads();
    if (tid == 0)
        __hip_atomic_fetch_add(myflag, 1, __ATOMIC_RELAXED, __HIP_MEMORY_SCOPE_AGENT);

    const int gb = tid >> 3, hp = tid & 7;
    const int hg = g*16 + hp*2;
    const int r0 = mgrp*32 + lr, r1 = r0 + 16;
    const int ab0 = r0 & 63, ab1 = r1 & 63;
    const int v0_ = r0 >> 6, v1_ = r1 >> 6;
    const bool pure2 = (mgrp >= 2);
    int* const pollp = flagbase + (lane & 31)*32;

    float2 h1prev;
    {
        const float* gr = gi + (size_t)gb*NS*H3;
        float o[2];
        #pragma unroll
        for (int u=0;u<2;u++){
            int h = hg+u;
            float rr = sigmf(gr[h] + gh0[h]);
            float zz = sigmf(gr[512+h] + gh0[512+h]);
            float nn = tanhf(gr[1024+h] + rr*gh0[1024+h]);
            o[u] = (1.f-zz)*nn + zz*h0v[h];
        }
        h1prev = make_float2(o[0], o[1]);
    }
    float2 nx0 = *(const float2*)(gi + ((size_t)gb*NS + 1)*H3 + hg);
    float2 nx1 = *(const float2*)(gi + ((size_t)gb*NS + 1)*H3 + 512 + hg);
    float2 nx2 = *(const float2*)(gi + ((size_t)gb*NS + 1)*H3 + 1024 + hg);
    float2 nxA = *(const float2*)(alpha + ((size_t)gb*NS + 1)*2);

    bool earlyN = false;
    short8 a0[8], a1[8];

    for (int i = 1; i < NS; i++){
        if (w == 0){
            int spins = 0;
            while (1){
                int v = __hip_atomic_load(pollp, __ATOMIC_RELAXED, __HIP_MEMORY_SCOPE_AGENT);
                if (__all(v >= i)) break;
                if (++spins > (1<<19)) break;
            }
            if (lane == 0 && g == 0)
                __hip_atomic_fetch_add(progp, 1, __ATOMIC_RELAXED, __HIP_MEMORY_SCOPE_AGENT);
        }
        __syncthreads();
        float2 cg0 = nx0, cg1 = nx1, cg2 = nx2, cA = nxA;
        if (!earlyN){
            int s0 = v0_ ? (int)U.S.idx8[ab0*NS + i] : (i-1);
            int s1 = v1_ ? (int)U.S.idx8[ab1*NS + i] : (i-1);
            const unsigned short* ap0 = xb + ((size_t)ab0*NS + s0)*NH + kh*256 + lk*8;
            const unsigned short* ap1 = xb + ((size_t)ab1*NS + s1)*NH + kh*256 + lk*8;
            LD16C(a0[0], ap0, "0");   LD16C(a0[1], ap0, "64");  LD16C(a0[2], ap0, "128"); LD16C(a0[3], ap0, "192");
            LD16C(a0[4], ap0, "256"); LD16C(a0[5], ap0, "320"); LD16C(a0[6], ap0, "384"); LD16C(a0[7], ap0, "448");
            LD16C(a1[0], ap1, "0");   LD16C(a1[1], ap1, "64");  LD16C(a1[2], ap1, "128"); LD16C(a1[3], ap1, "192");
            LD16C(a1[4], ap1, "256"); LD16C(a1[5], ap1, "320"); LD16C(a1[6], ap1, "384"); LD16C(a1[7], ap1, "448");
        }
        asm volatile("s_waitcnt vmcnt(0)" ::: "memory");
        __builtin_amdgcn_sched_barrier(0);
        f32x4 acc00 = {}, acc01 = {}, acc02 = {}, acc10 = {}, acc11 = {}, acc12 = {};
        #pragma unroll
        for (int ks=0; ks<8; ks++){
            acc00 = __builtin_amdgcn_mfma_f32_16x16x32_bf16(a0[ks], bw0[ks], acc00, 0,0,0);
            acc01 = __builtin_amdgcn_mfma_f32_16x16x32_bf16(a0[ks], bw1[ks], acc01, 0,0,0);
            acc02 = __builtin_amdgcn_mfma_f32_16x16x32_bf16(a0[ks], bw2[ks], acc02, 0,0,0);
            acc10 = __builtin_amdgcn_mfma_f32_16x16x32_bf16(a1[ks], bw0[ks], acc10, 0,0,0);
            acc11 = __builtin_amdgcn_mfma_f32_16x16x32_bf16(a1[ks], bw1[ks], acc11, 0,0,0);
            acc12 = __builtin_amdgcn_mfma_f32_16x16x32_bf16(a1[ks], bw2[ks], acc12, 0,0,0);
        }
        {
            int ip = (i+1 < NS) ? (i+1) : (NS-1);
            nx0 = *(const float2*)(gi + ((size_t)gb*NS + ip)*H3 + hg);
            nx1 = *(const float2*)(gi + ((size_t)gb*NS + ip)*H3 + 512 + hg);
            nx2 = *(const float2*)(gi + ((size_t)gb*NS + ip)*H3 + 1024 + hg);
            nxA = *(const float2*)(alpha + ((size_t)gb*NS + ip)*2);
        }
        #pragma unroll
        for (int j=0;j<4;j++){
            int m0 = mgrp*32 + lk*4 + j, m1 = m0 + 16;
            U.S.ghs[kh][m0][lr]    = acc00[j];
            U.S.ghs[kh][m0][16+lr] = acc01[j];
            U.S.ghs[kh][m0][32+lr] = acc02[j];
            U.S.ghs[kh][m1][lr]    = acc10[j];
            U.S.ghs[kh][m1][16+lr] = acc11[j];
            U.S.ghs[kh][m1][32+lr] = acc12[j];
        }
        __syncthreads();
        {
            int rid = U.S.idx8[gb*NS + i];
            float2 h2p = *(const float2*)(xf + ((size_t)gb*NS + rid)*NH + hg);
            float o0, o1;
            #pragma unroll
            for (int u=0; u<2; u++){
                int hl = hp*2 + u;
                float g1r = U.S.ghs[0][gb][hl]       + U.S.ghs[1][gb][hl]       + U.S.bhs[hl];
                float g1z = U.S.ghs[0][gb][16+hl]    + U.S.ghs[1][gb][16+hl]    + U.S.bhs[16+hl];
                float g1n = U.S.ghs[0][gb][32+hl]    + U.S.ghs[1][gb][32+hl]    + U.S.bhs[32+hl];
                float g2r = U.S.ghs[0][64+gb][hl]    + U.S.ghs[1][64+gb][hl]    + U.S.bhs[hl];
                float g2z = U.S.ghs[0][64+gb][16+hl] + U.S.ghs[1][64+gb][16+hl] + U.S.bhs[16+hl];
                float g2n = U.S.ghs[0][64+gb][32+hl] + U.S.ghs[1][64+gb][32+hl] + U.S.bhs[32+hl];
                float ir  = u ? cg0.y : cg0.x;
                float iz  = u ? cg1.y : cg1.x;
                float inn = u ? cg2.y : cg2.x;
                float hh1 = u ? h1prev.y : h1prev.x;
                float hh2 = u ? h2p.y : h2p.x;
                float r1v = sigmf(ir + g1r), z1 = sigmf(iz + g1z);
                float n1 = tanhf(inn + r1v*g1n);
                float hid1 = (1.f-z1)*n1 + z1*hh1;
                float r2v = sigmf(ir + g2r), z2 = sigmf(iz + g2z);
                float n2 = tanhf(inn + r2v*g2n);
                float hid2 = (1.f-z2)*n2 + z2*hh2;
                float v = cA.x*hid1 + cA.y*hid2;
                if (u) o1 = v; else o0 = v;
            }
            *(float2*)(xf + ((size_t)gb*NS + i)*NH + hg) = make_float2(o0, o1);
            unsigned pk = (unsigned)f2bf(o0) | ((unsigned)f2bf(o1) << 16);
            unsigned short* xaddr  = xb  + ((size_t)gb*NS + i)*NH + hg;
            unsigned short* xaddr2 = xb2 + ((size_t)gb*NS + i)*NH + hg;
            asm volatile("global_store_dword %0, %1, off sc0" :: "v"(xaddr), "v"(pk) : "memory");
            asm volatile("global_store_dword %0, %1, off sc0 sc1" :: "v"(xaddr2), "v"(pk) : "memory");
            h1prev = make_float2(o0, o1);
        }
        asm volatile("s_waitcnt vmcnt(0)" ::: "memory");
        __syncthreads();
        if (tid == 0)
            __hip_atomic_fetch_add(myflag, 1, __ATOMIC_RELAXED, __HIP_MEMORY_SCOPE_AGENT);
        earlyN = false;
        if (pure2 && (i+1 < NS)){
            int s0n = (int)U.S.idx8[ab0*NS + i+1];
            int s1n = (int)U.S.idx8[ab1*NS + i+1];
            if (__all((s0n <= i-1) && (s1n <= i-1))){
                earlyN = true;
                const unsigned short* ap0 = xb + ((size_t)ab0*NS + s0n)*NH + kh*256 + lk*8;
                const unsigned short* ap1 = xb + ((size_t)ab1*NS + s1n)*NH + kh*256 + lk*8;
                LD16C(a0[0], ap0, "0");   LD16C(a0[1], ap0, "64");  LD16C(a0[2], ap0, "128"); LD16C(a0[3], ap0, "192");
                LD16C(a0[4], ap0, "256"); LD16C(a0[5], ap0, "320"); LD16C(a0[6], ap0, "384"); LD16C(a0[7], ap0, "448");
                LD16C(a1[0], ap1, "0");   LD16C(a1[1], ap1, "64");  LD16C(a1[2], ap1, "128"); LD16C(a1[3], ap1, "192");
                LD16C(a1[4], ap1, "256"); LD16C(a1[5], ap1, "320"); LD16C(a1[6], ap1, "384"); LD16C(a1[7], ap1, "448");
            }
        }
    }
    // publish final progress (= NS) after confirming all flags done
    if (g == 0){
        if (w == 0){
            int spins = 0;
            while (1){
                int v = __hip_atomic_load(pollp, __ATOMIC_RELAXED, __HIP_MEMORY_SCOPE_AGENT);
                if (__all(v >= NS)) break;
                if (++spins > (1<<20)) break;
            }
            if (lane == 0)
                __hip_atomic_fetch_add(progp, 1, __ATOMIC_RELAXED, __HIP_MEMORY_SCOPE_AGENT);
        }
    }
}

__global__ void k_time(const float* __restrict__ xf, const float* __restrict__ W_time,
                       const float* __restrict__ b_time, float* __restrict__ out){
    int gw = (int)((blockIdx.x*(size_t)blockDim.x + threadIdx.x) >> 6);
    int lane = threadIdx.x & 63;
    if (gw >= NB*NS) return;
    const float* x = xf + (size_t)gw*NH;
    float s = 0.f;
    for (int k=lane;k<NH;k+=64) s += x[k]*W_time[k];
    for (int off=32; off; off>>=1) s += __shfl_down(s, off);
    if (lane == 0) out[gw] = s + b_time[0];
}

extern "C" void kernel_launch(void* const* d_in, const int* in_sizes, int n_in,
                              void* d_out, int out_size, void* d_ws, size_t ws_size,
                              hipStream_t stream){
    const float* src    = (const float*)d_in[0];
    const int*   lens   = (const int*)d_in[1];
    const int*   seq    = (const int*)d_in[2];
    const float* X      = (const float*)d_in[3];
    const float* A      = (const float*)d_in[4];
    const float* W_attn = (const float*)d_in[5];
    const float* a_attn = (const float*)d_in[6];
    const float* W_ih   = (const float*)d_in[7];
    const float* W_hh   = (const float*)d_in[8];
    const float* b_ih   = (const float*)d_in[9];
    const float* b_hh   = (const float*)d_in[10];
    const float* h0     = (const float*)d_in[11];
    const float* W_poi  = (const float*)d_in[12];
    const float* b_poi  = (const float*)d_in[13];
    const float* W_time = (const float*)d_in[14];
    const float* b_time = (const float*)d_in[15];
    const float* W_cat  = (const float*)d_in[16];
    const float* b_cat  = (const float*)d_in[17];

    char* ws = (char*)d_ws;
    float*          xf      = (float*)(ws + XF_OFF);
    unsigned short* xb      = (unsigned short*)(ws + XB_OFF);
    unsigned short* Whh_bf  = (unsigned short*)(ws + WHH_OFF);
    double*         wh1     = (double*)(ws + WH1_OFF);
    double*         wh2     = (double*)(ws + WH2_OFF);
    float*          alpha   = (float*)(ws + AL_OFF);
    int*            idx     = (int*)(ws + IDX_OFF);
    float*          gh0     = (float*)(ws + GH0_OFF);
    int*            ctrl    = (int*)(ws + CTRL_OFF);
    unsigned short* Wpoi_bf = (unsigned short*)(ws + WPOI_OFF);
    unsigned short* Wcat_bf = (unsigned short*)(ws + WCAT_OFF);

    int overlap = (ws_size >= (size_t)WS_NEED) ? 1 : 0;
    unsigned short* xb2 = (ws_size >= (size_t)WS_NEED2) ? (unsigned short*)(ws + XB2_OFF) : xb;

    char* ob = (char*)d_out;
    unsigned short* src_bf = (unsigned short*)(ob + 0);         // dead before C writes
    unsigned short* Wih_bf = (unsigned short*)(ob + 9437184);
    float* gi = overlap ? (float*)(ws + GI_OFF) : (float*)(ob + 16777216);

    float* out_poi  = (float*)d_out;
    float* out_time = (float*)d_out + (size_t)8192*8192;
    float* out_cat  = out_time + 8192;

    k_init<<<4096, 256, 0, stream>>>(ctrl, src, src_bf, W_ih, Wih_bf, W_hh, Whh_bf,
                                     W_poi, Wpoi_bf, W_cat, Wcat_bf);
    k_wh<<<38, 256, 0, stream>>>(X, W_attn, a_attn, wh1, wh2, h0, W_hh, b_hh, gh0);
    k_attn<<<2048, 256, 0, stream>>>(seq, lens, A, wh1, wh2, alpha, idx);

    k_gemm_bf16<<<dim3(12, 64), 256, 0, stream>>>(src_bf, Wih_bf, b_ih, gi, NB*NS, H3, NE, H3);

    k_mega<<<NWG_LAUNCH, 512, 0, stream>>>(gi, Whh_bf, b_hh, alpha, idx, gh0, h0,
                                           xf, xb, xb2, ctrl, Wpoi_bf, b_poi, Wcat_bf, b_cat,
                                           out_poi, out_cat, overlap);

    k_time<<<2048, 256, 0, stream>>>(xf, W_time, b_time, out_time);
}